// Round 7
// baseline (554.482 us; speedup 1.0000x reference)
//
#include <hip/hip_runtime.h>
#include <hip/hip_bf16.h>

#define DD 64
#define NBLK 128          // partition pass blocks (each owns a contiguous edge chunk)
#define MAXBUK 1024       // max buckets => supports n <= 131072 (problem: n = 100000)
#define BSHIFT 7          // 128 nodes per bucket

typedef __attribute__((ext_vector_type(8))) short short8v;  // 8 bf16 MFMA A/B frag
typedef __attribute__((ext_vector_type(4))) float f32x4;    // MFMA C/D frag

__device__ __forceinline__ unsigned pk_bf16(float a, float b) {
    __hip_bfloat162 h = __float22bfloat162_rn(make_float2(a, b));
    unsigned u; __builtin_memcpy(&u, &h, 4); return u;
}
__device__ __forceinline__ short f2bf_s(float f) {   // RNE scalar (startup only)
    union { float f; unsigned u; } x; x.f = f;
    unsigned r = x.u + 0x7fff + ((x.u >> 16) & 1);
    return (short)(r >> 16);
}
__device__ __forceinline__ float bf_lo(unsigned u) { return __int_as_float(u << 16); }
__device__ __forceinline__ float bf_hi(unsigned u) { return __int_as_float(u & 0xffff0000u); }
__device__ __forceinline__ short8v u4_to_s8(uint4 u) {
    union { uint4 u; short8v s; } x; x.u = u; return x.s;
}
// 2-phase scan: final offset = blockwise-exclusive + block base (no scan3 pass)
__device__ __forceinline__ int ofs_at(const int* __restrict__ c,
                                      const int* __restrict__ bs, int i) {
    return c[i] + bs[i >> 8];
}

// =====================================================================
// CSR build, original node space — zero global atomics, 5 dispatches.
// R7: scale fused into bucket_all; gcn gets dynamic work-stealing
// (R6 counters: Occupancy 16% of 50% static = quantization tail,
//  1.53 groups/wave rounded to 1-or-2).
// =====================================================================

__global__ __launch_bounds__(256) void part_count(
        const int* __restrict__ src, const int* __restrict__ dst,
        int* __restrict__ cnt, int* __restrict__ wctr, int E, int nbuk, int ce) {
    __shared__ int hd[MAXBUK], hs[MAXBUK];
    if (blockIdx.x == 0 && threadIdx.x < 3) wctr[threadIdx.x] = 0;  // gcn steal ctrs
    for (int i = threadIdx.x; i < MAXBUK; i += 256) { hd[i] = 0; hs[i] = 0; }
    __syncthreads();
    int e0 = blockIdx.x * ce;
    int e1 = min(e0 + ce, E);
    for (int e = e0 + (int)threadIdx.x; e < e1; e += 256) {
        atomicAdd(&hd[dst[e] >> BSHIFT], 1);
        atomicAdd(&hs[src[e] >> BSHIFT], 1);
    }
    __syncthreads();
    int L2 = nbuk * NBLK;
    // [bucket][block] layout -> flat exclusive scan yields global offsets
    for (int b = threadIdx.x; b < nbuk; b += 256) {
        cnt[b * NBLK + blockIdx.x]      = hd[b];
        cnt[L2 + b * NBLK + blockIdx.x] = hs[b];
    }
}

__global__ void scan1p(int* __restrict__ a, int* __restrict__ bsums, int L) {
    __shared__ int tmp[256];
    int gid = blockIdx.x * 256 + threadIdx.x;
    int v = (gid < L) ? a[gid] : 0;
    tmp[threadIdx.x] = v;
    __syncthreads();
    for (int off = 1; off < 256; off <<= 1) {
        int t = (threadIdx.x >= off) ? tmp[threadIdx.x - off] : 0;
        __syncthreads();
        tmp[threadIdx.x] += t;
        __syncthreads();
    }
    if (gid < L) a[gid] = tmp[threadIdx.x] - v;
    if (threadIdx.x == 255) bsums[blockIdx.x] = tmp[255];
}
__global__ void scan2p(int* __restrict__ bsums, int nb) {
    __shared__ int tmp[1024];
    int v = (threadIdx.x < (unsigned)nb) ? bsums[threadIdx.x] : 0;
    tmp[threadIdx.x] = v;
    __syncthreads();
    for (int off = 1; off < 1024; off <<= 1) {
        int t = (threadIdx.x >= off) ? tmp[threadIdx.x - off] : 0;
        __syncthreads();
        tmp[threadIdx.x] += t;
        __syncthreads();
    }
    if (threadIdx.x < (unsigned)nb) bsums[threadIdx.x] = tmp[threadIdx.x] - v;
}

__global__ __launch_bounds__(256) void part_scatter(
        const int* __restrict__ src, const int* __restrict__ dst,
        const int* __restrict__ cnt, const int* __restrict__ bsA,
        unsigned int* __restrict__ partD, unsigned char* __restrict__ partS,
        int E, int nbuk, int ce) {
    __shared__ int cd[MAXBUK], cs[MAXBUK];
    int L2 = nbuk * NBLK;
    for (int b = threadIdx.x; b < nbuk; b += 256) {
        cd[b] = ofs_at(cnt, bsA, b * NBLK + blockIdx.x);
        cs[b] = ofs_at(cnt, bsA, L2 + b * NBLK + blockIdx.x) - E;
    }
    __syncthreads();
    int e0 = blockIdx.x * ce;
    int e1 = min(e0 + ce, E);
    for (int e = e0 + (int)threadIdx.x; e < e1; e += 256) {
        int s = src[e], d = dst[e];
        int pd = atomicAdd(&cd[d >> BSHIFT], 1);
        partD[pd] = ((unsigned)(d & 127) << 17) | (unsigned)s;
        int ps = atomicAdd(&cs[s >> BSHIFT], 1);
        partS[ps] = (unsigned char)(s & 127);
    }
}

// ---- fused per-bucket finalize: in-hist -> rowptr/inn + esrc scatter,
//      out-hist -> outn/rs, AND hs = feats*outn (scale fused, R7). ----
__global__ __launch_bounds__(256) void bucket_all(
        const unsigned int* __restrict__ partD, const unsigned char* __restrict__ partS,
        const int* __restrict__ cnt, const int* __restrict__ bsA,
        const float* __restrict__ feats,
        int* __restrict__ rowptr, int* __restrict__ esrc,
        float* __restrict__ inn, float* __restrict__ outn, float* __restrict__ rs,
        unsigned short* __restrict__ hsv,
        int E, int nbuk, int n) {
    __shared__ int hi[128], sc[128], cu[128], ho[128];
    __shared__ float son[128];
    int b = blockIdx.x, tid = threadIdx.x;
    int L2 = nbuk * NBLK;
    int e0 = ofs_at(cnt, bsA, b * NBLK);
    int e1 = (b + 1 < nbuk) ? ofs_at(cnt, bsA, (b + 1) * NBLK) : E;
    int f0 = ofs_at(cnt, bsA, L2 + b * NBLK) - E;
    int f1 = (b + 1 < nbuk) ? ofs_at(cnt, bsA, L2 + (b + 1) * NBLK) - E : E;
    if (tid < 128) { hi[tid] = 0; ho[tid] = 0; }
    __syncthreads();
    for (int e = e0 + tid; e < e1; e += 256) atomicAdd(&hi[partD[e] >> 17], 1);
    for (int e = f0 + tid; e < f1; e += 256) atomicAdd(&ho[(int)partS[e]], 1);
    __syncthreads();
    if (tid < 128) sc[tid] = hi[tid];
    __syncthreads();
    for (int off = 1; off < 128; off <<= 1) {
        int t = (tid < 128 && tid >= off) ? sc[tid - off] : 0;
        __syncthreads();
        if (tid < 128) sc[tid] += t;
        __syncthreads();
    }
    int nodeBase = b << BSHIFT;
    if (tid < 128) {
        int excl = e0 + sc[tid] - hi[tid];
        cu[tid] = excl;
        float oc = (float)max(ho[tid], 1);
        float on = rsqrtf(oc);
        son[tid] = on;
        int v = nodeBase + tid;
        if (v < n) {
            rowptr[v] = excl;
            inn[v] = rsqrtf((float)max(hi[tid], 1));
            outn[v] = on;
            rs[v]   = sqrtf(oc);
        }
    }
    if (b == 0 && tid == 0) rowptr[n] = E;
    __syncthreads();
    // esrc scatter
    for (int e = e0 + tid; e < e1; e += 256) {
        unsigned u = partD[e];
        int p = atomicAdd(&cu[u >> 17], 1);
        esrc[p] = (int)(u & 0x1FFFFu);
    }
    // fused scale: hs[v] = bf16(feats[v] * outn[v]) for the 128 bucket nodes
    for (int idx = tid; idx < 128 * 8; idx += 256) {
        int vl = idx >> 3, c = idx & 7;
        int v = nodeBase + vl;
        if (v < n) {
            float s = son[vl];
            const float4* fp = (const float4*)(feats + (size_t)v * DD) + c * 2;
            float4 g0 = fp[0], g1 = fp[1];
            uint4 o;
            o.x = pk_bf16(g0.x * s, g0.y * s); o.y = pk_bf16(g0.z * s, g0.w * s);
            o.z = pk_bf16(g1.x * s, g1.y * s); o.w = pk_bf16(g1.z * s, g1.w * s);
            *(uint4*)&hsv[(size_t)v * DD + c * 8] = o;
        }
    }
}

// ---------------- fused per-layer kernel (R6 body + dynamic stealing) -------
__global__ __launch_bounds__(256) void gcn_kernel(
    const int* __restrict__ rowptr, const int* __restrict__ esrc,
    const float* __restrict__ inn, const float* __restrict__ rs,
    const float* __restrict__ outn,
    const unsigned short* __restrict__ hs_in,
    const float* __restrict__ Wc, const float* __restrict__ bc,
    const float* __restrict__ Wr, const float* __restrict__ br,
    const float* __restrict__ Wp, const float* __restrict__ pb,
    const float* __restrict__ g, const float* __restrict__ bb,
    unsigned short* __restrict__ hs_out, float* __restrict__ h_final,
    float* __restrict__ pred_out, int* __restrict__ wctr,
    int first, int last, int n)
{
    __shared__ __align__(16) short sWf[24 * 64 * 8];  // 24 A-frags (Wc|Wr|Wp) x 64 lanes x 8 bf16
    __shared__ __align__(16) short sXa[4][16 * 72];   // per-wave 16-node bf16 rows (72-short pad)
    __shared__ float sEps[4 * 64];                    // bias | ln_g | ln_b | pred_b

    int lane = threadIdx.x & 63;
    int wave = threadIdx.x >> 6;        // 0..3
    int q   = lane & 15;                // mfma: node id
    int gg  = lane >> 4;                // mfma: k/feat quad
    int q8  = lane & 7;                 // gather: 16B chunk (feats q8*8..+7)
    int o8  = lane >> 3;                // gather: node-in-half 0..7

    for (int idx = threadIdx.x; idx < 64; idx += blockDim.x) {
        sEps[idx]       = bc[idx] + br[idx];
        sEps[64 + idx]  = g[idx];
        sEps[128 + idx] = bb[idx];
        sEps[192 + idx] = pb[idx];
    }
    // A-frags: f = mat*8 + ft*2 + kc ; elem j = W[kc*32+gg*8+j][ft*16+q]
    for (int f = wave * 6; f < wave * 6 + 6; ++f) {
        int mat = f >> 3, ft = (f >> 1) & 3, kc = f & 1;
        const float* Ws = (mat == 0) ? Wc : (mat == 1) ? Wr : Wp;
        int feat = ft * 16 + q;
        int k0 = kc * 32 + gg * 8;
        short8v fr;
        #pragma unroll
        for (int j = 0; j < 8; ++j) fr[j] = f2bf_s(Ws[(k0 + j) * DD + feat]);
        *(short8v*)&sWf[(f * 64 + lane) * 8] = fr;
    }
    __syncthreads();

    short* xrow_w = &sXa[wave][0];
    const short8v* wf = (const short8v*)sWf;
    int ngrp = (n + 15) >> 4;

    // dynamic work-stealing: one 16-node group per atomic fetch (R7)
    int grp = 0;
    if (lane == 0) grp = atomicAdd(wctr, 1);
    grp = __shfl(grp, 0);

    while (grp < ngrp) {
        // prefetch next group id (latency hidden under the gather)
        int gnext = 0;
        if (lane == 0) gnext = atomicAdd(wctr, 1);

        int vbase = grp << 4;
        int vo = vbase + q;
        int vsel = min(vo, n - 1);

        // self row B-frags (raw bf16), issued early to overlap gather
        const uint4* hrow = (const uint4*)(hs_in + (size_t)vsel * DD);
        uint4 bh0u = hrow[gg];
        uint4 bh1u = hrow[4 + gg];
        float rsv  = rs[vsel];
        float innv = inn[vsel];

        // rowptr for the 16 nodes; per-lane start/deg for both halves
        int rp = rowptr[min(vbase + min(lane, 16), n)];
        int stA = __shfl(rp, o8);     int dgA = __shfl(rp, o8 + 1) - stA;
        int stB = __shfl(rp, o8 + 8); int dgB = __shfl(rp, o8 + 9) - stB;

        #pragma unroll
        for (int hh = 0; hh < 2; ++hh) {
            int st = hh ? stB : stA;
            int dg = hh ? dgB : dgA;
            // wave-uniform max degree over this half's 8 nodes
            int mdg = dg;
            mdg = max(mdg, __shfl_xor(mdg, 8));
            mdg = max(mdg, __shfl_xor(mdg, 16));
            mdg = max(mdg, __shfl_xor(mdg, 32));

            float a[8];
            #pragma unroll
            for (int c = 0; c < 8; ++c) a[c] = 0.0f;

            int id0 = (0 < dg) ? esrc[st + 0] : 0;  float m0 = (0 < dg) ? 1.f : 0.f;
            int id1 = (1 < dg) ? esrc[st + 1] : 0;  float m1 = (1 < dg) ? 1.f : 0.f;
            int id2 = (2 < dg) ? esrc[st + 2] : 0;  float m2 = (2 < dg) ? 1.f : 0.f;
            int id3 = (3 < dg) ? esrc[st + 3] : 0;  float m3 = (3 < dg) ? 1.f : 0.f;

            for (int t = 0; t < mdg; t += 4) {
                // 4 independent 16B row-chunk loads (wave: 4 x 1KB coalesced)
                uint4 r0 = *(const uint4*)(hs_in + (size_t)id0 * DD + q8 * 8);
                uint4 r1 = *(const uint4*)(hs_in + (size_t)id1 * DD + q8 * 8);
                uint4 r2 = *(const uint4*)(hs_in + (size_t)id2 * DD + q8 * 8);
                uint4 r3 = *(const uint4*)(hs_in + (size_t)id3 * DD + q8 * 8);
                float c0 = m0, c1 = m1, c2 = m2, c3 = m3;
                // prefetch next 4 edge indices (overlap row loads)
                int t4 = t + 4;
                id0 = (t4 + 0 < dg) ? esrc[st + t4 + 0] : 0;  m0 = (t4 + 0 < dg) ? 1.f : 0.f;
                id1 = (t4 + 1 < dg) ? esrc[st + t4 + 1] : 0;  m1 = (t4 + 1 < dg) ? 1.f : 0.f;
                id2 = (t4 + 2 < dg) ? esrc[st + t4 + 2] : 0;  m2 = (t4 + 2 < dg) ? 1.f : 0.f;
                id3 = (t4 + 3 < dg) ? esrc[st + t4 + 3] : 0;  m3 = (t4 + 3 < dg) ? 1.f : 0.f;
                // accumulate
                a[0] = fmaf(bf_lo(r0.x), c0, a[0]); a[1] = fmaf(bf_hi(r0.x), c0, a[1]);
                a[2] = fmaf(bf_lo(r0.y), c0, a[2]); a[3] = fmaf(bf_hi(r0.y), c0, a[3]);
                a[4] = fmaf(bf_lo(r0.z), c0, a[4]); a[5] = fmaf(bf_hi(r0.z), c0, a[5]);
                a[6] = fmaf(bf_lo(r0.w), c0, a[6]); a[7] = fmaf(bf_hi(r0.w), c0, a[7]);
                a[0] = fmaf(bf_lo(r1.x), c1, a[0]); a[1] = fmaf(bf_hi(r1.x), c1, a[1]);
                a[2] = fmaf(bf_lo(r1.y), c1, a[2]); a[3] = fmaf(bf_hi(r1.y), c1, a[3]);
                a[4] = fmaf(bf_lo(r1.z), c1, a[4]); a[5] = fmaf(bf_hi(r1.z), c1, a[5]);
                a[6] = fmaf(bf_lo(r1.w), c1, a[6]); a[7] = fmaf(bf_hi(r1.w), c1, a[7]);
                a[0] = fmaf(bf_lo(r2.x), c2, a[0]); a[1] = fmaf(bf_hi(r2.x), c2, a[1]);
                a[2] = fmaf(bf_lo(r2.y), c2, a[2]); a[3] = fmaf(bf_hi(r2.y), c2, a[3]);
                a[4] = fmaf(bf_lo(r2.z), c2, a[4]); a[5] = fmaf(bf_hi(r2.z), c2, a[5]);
                a[6] = fmaf(bf_lo(r2.w), c2, a[6]); a[7] = fmaf(bf_hi(r2.w), c2, a[7]);
                a[0] = fmaf(bf_lo(r3.x), c3, a[0]); a[1] = fmaf(bf_hi(r3.x), c3, a[1]);
                a[2] = fmaf(bf_lo(r3.y), c3, a[2]); a[3] = fmaf(bf_hi(r3.y), c3, a[3]);
                a[4] = fmaf(bf_lo(r3.z), c3, a[4]); a[5] = fmaf(bf_hi(r3.z), c3, a[5]);
                a[6] = fmaf(bf_lo(r3.w), c3, a[6]); a[7] = fmaf(bf_hi(r3.w), c3, a[7]);
            }

            // lane holds its node-chunk's final raw sums; pack + one LDS write
            uint4 w4;
            w4.x = pk_bf16(a[0], a[1]); w4.y = pk_bf16(a[2], a[3]);
            w4.z = pk_bf16(a[4], a[5]); w4.w = pk_bf16(a[6], a[7]);
            *(uint4*)&xrow_w[(hh * 8 + o8) * 72 + q8 * 8] = w4;
        }

        // ---- B-frags + 16 MFMA (separate conv/res accumulators) ----
        const short* xr = &xrow_w[q * 72];
        short8v ba0 = *(const short8v*)&xr[gg * 8];
        short8v ba1 = *(const short8v*)&xr[32 + gg * 8];
        short8v sh0 = u4_to_s8(bh0u);
        short8v sh1 = u4_to_s8(bh1u);

        f32x4 accC[4], accR[4];
        #pragma unroll
        for (int ft = 0; ft < 4; ++ft) {
            f32x4 c = {0.f, 0.f, 0.f, 0.f};
            c = __builtin_amdgcn_mfma_f32_16x16x32_bf16(wf[(ft * 2 + 0) * 64 + lane], ba0, c, 0, 0, 0);
            c = __builtin_amdgcn_mfma_f32_16x16x32_bf16(wf[(ft * 2 + 1) * 64 + lane], ba1, c, 0, 0, 0);
            accC[ft] = c;
            f32x4 r = {0.f, 0.f, 0.f, 0.f};
            r = __builtin_amdgcn_mfma_f32_16x16x32_bf16(wf[(8 + ft * 2 + 0) * 64 + lane], sh0, r, 0, 0, 0);
            r = __builtin_amdgcn_mfma_f32_16x16x32_bf16(wf[(8 + ft * 2 + 1) * 64 + lane], sh1, r, 0, 0, 0);
            accR[ft] = r;
        }

        // ---- combine (inn*conv + rs*res + bias) + LayerNorm + relu ----
        f32x4 ac[4];
        #pragma unroll
        for (int ft = 0; ft < 4; ++ft) {
            float4 b4 = *(const float4*)&sEps[ft * 16 + gg * 4];
            ac[ft][0] = fmaf(innv, accC[ft][0], fmaf(rsv, accR[ft][0], b4.x));
            ac[ft][1] = fmaf(innv, accC[ft][1], fmaf(rsv, accR[ft][1], b4.y));
            ac[ft][2] = fmaf(innv, accC[ft][2], fmaf(rsv, accR[ft][2], b4.z));
            ac[ft][3] = fmaf(innv, accC[ft][3], fmaf(rsv, accR[ft][3], b4.w));
        }
        float s = 0.f;
        #pragma unroll
        for (int ft = 0; ft < 4; ++ft) s += ac[ft][0] + ac[ft][1] + ac[ft][2] + ac[ft][3];
        s += __shfl_xor(s, 16); s += __shfl_xor(s, 32);
        float mu = s * (1.0f / 64.0f);
        float vsum = 0.f;
        #pragma unroll
        for (int ft = 0; ft < 4; ++ft) {
            #pragma unroll
            for (int r = 0; r < 4; ++r) { float d = ac[ft][r] - mu; vsum += d * d; }
        }
        vsum += __shfl_xor(vsum, 16); vsum += __shfl_xor(vsum, 32);
        float rinv = rsqrtf(vsum * (1.0f / 64.0f) + 1e-5f);

        float4 yv[4];
        #pragma unroll
        for (int ft = 0; ft < 4; ++ft) {
            float4 g4 = *(const float4*)&sEps[64 + ft * 16 + gg * 4];
            float4 c4 = *(const float4*)&sEps[128 + ft * 16 + gg * 4];
            yv[ft].x = fmaxf((ac[ft][0] - mu) * rinv * g4.x + c4.x, 0.f);
            yv[ft].y = fmaxf((ac[ft][1] - mu) * rinv * g4.y + c4.y, 0.f);
            yv[ft].z = fmaxf((ac[ft][2] - mu) * rinv * g4.z + c4.z, 0.f);
            yv[ft].w = fmaxf((ac[ft][3] - mu) * rinv * g4.w + c4.w, 0.f);
        }

        if (!last) {
            if (vo < n) {
                float on = outn[vo];
                #pragma unroll
                for (int ft = 0; ft < 4; ++ft) {
                    size_t off = (size_t)vo * DD + ft * 16 + gg * 4;
                    uint2 p;
                    p.x = pk_bf16(yv[ft].x * on, yv[ft].y * on);
                    p.y = pk_bf16(yv[ft].z * on, yv[ft].w * on);
                    *(uint2*)&hs_out[off] = p;
                    if (first) {
                        *(float4*)&h_final[off] = yv[ft];
                    } else {
                        float4 hf = *(const float4*)&h_final[off];
                        hf.x += yv[ft].x; hf.y += yv[ft].y;
                        hf.z += yv[ft].z; hf.w += yv[ft].w;
                        *(float4*)&h_final[off] = hf;
                    }
                }
            }
        } else {
            // fused prediction: hf = h_final + y -> LDS (bf16) -> B-frags -> 8 MFMA -> d_out
            #pragma unroll
            for (int ft = 0; ft < 4; ++ft) {
                float4 hf = make_float4(0.f, 0.f, 0.f, 0.f);
                if (vo < n) {
                    float4 old = *(const float4*)&h_final[(size_t)vo * DD + ft * 16 + gg * 4];
                    hf.x = old.x + yv[ft].x; hf.y = old.y + yv[ft].y;
                    hf.z = old.z + yv[ft].z; hf.w = old.w + yv[ft].w;
                }
                uint2 p;
                p.x = pk_bf16(hf.x, hf.y);
                p.y = pk_bf16(hf.z, hf.w);
                *(uint2*)&xrow_w[q * 72 + ft * 16 + gg * 4] = p;   // same-wave DS, in order
            }
            short8v bp0 = *(const short8v*)&xr[gg * 8];
            short8v bp1 = *(const short8v*)&xr[32 + gg * 8];
            #pragma unroll
            for (int ft = 0; ft < 4; ++ft) {
                f32x4 p = {0.f, 0.f, 0.f, 0.f};
                p = __builtin_amdgcn_mfma_f32_16x16x32_bf16(wf[(16 + ft * 2 + 0) * 64 + lane], bp0, p, 0, 0, 0);
                p = __builtin_amdgcn_mfma_f32_16x16x32_bf16(wf[(16 + ft * 2 + 1) * 64 + lane], bp1, p, 0, 0, 0);
                if (vo < n) {
                    float4 b4 = *(const float4*)&sEps[192 + ft * 16 + gg * 4];
                    float4 o = make_float4(p[0] + b4.x, p[1] + b4.y, p[2] + b4.z, p[3] + b4.w);
                    *(float4*)&pred_out[(size_t)vo * DD + ft * 16 + gg * 4] = o;
                }
            }
        }

        grp = __shfl(gnext, 0);
    }
}

extern "C" void kernel_launch(void* const* d_in, const int* in_sizes, int n_in,
                              void* d_out, int out_size, void* d_ws, size_t ws_size,
                              hipStream_t stream) {
    const float* feats  = (const float*)d_in[0];
    const int*   src    = (const int*)d_in[1];
    const int*   dst    = (const int*)d_in[2];
    const float* conv_W = (const float*)d_in[3];
    const float* conv_b = (const float*)d_in[4];
    const float* res_W  = (const float*)d_in[5];
    const float* res_b  = (const float*)d_in[6];
    const float* ln_g   = (const float*)d_in[7];
    const float* ln_b   = (const float*)d_in[8];
    const float* pred_W = (const float*)d_in[9];
    const float* pred_b = (const float*)d_in[10];

    int N = in_sizes[0] / DD;
    int E = in_sizes[1];

    int nbuk = (N + (1 << BSHIFT) - 1) >> BSHIFT;        // 782
    int ce   = (E + NBLK - 1) / NBLK;
    int L    = nbuk * NBLK * 2;                          // 200192
    int nb   = (L + 255) / 256;                          // 783 (<=1024 for scan2p)

    // ---- workspace layout (~58 MB) ----
    int*   rowptr = (int*)d_ws;                          // N+1
    int*   cnt    = rowptr + (N + 1);                    // MAXBUK*NBLK*2 (1 MB)
    int*   bsA    = cnt + MAXBUK * NBLK * 2;             // 1024
    int*   wctr   = bsA + 1024;                          // 3 (+pad to 256)
    int*   esrc   = wctr + 256;                          // E
    float* outn   = (float*)(esrc + E);                  // N
    float* inn    = outn + N;                            // N
    float* rs     = inn + N;                             // N
    float* base   = (float*)(((uintptr_t)(rs + N) + 15) & ~(uintptr_t)15);
    unsigned short* hsA = (unsigned short*)base;                     // N*64 bf16
    unsigned short* hsB = (unsigned short*)(base + (size_t)N * 32);  // N*64 bf16
    float* hfin  = base + (size_t)N * 64;                // N*64 fp32
    // partition scratch aliases hfin (dead before layer-0 writes hfin)
    unsigned int*  partD = (unsigned int*)hfin;                      // E uints
    unsigned char* partS = (unsigned char*)(partD + E);              // E bytes

    part_count  <<<NBLK, 256, 0, stream>>>(src, dst, cnt, wctr, E, nbuk, ce);
    scan1p      <<<nb, 256, 0, stream>>>(cnt, bsA, L);
    scan2p      <<<1, 1024, 0, stream>>>(bsA, nb);
    part_scatter<<<NBLK, 256, 0, stream>>>(src, dst, cnt, bsA, partD, partS, E, nbuk, ce);
    bucket_all  <<<nbuk, 256, 0, stream>>>(partD, partS, cnt, bsA, feats, rowptr, esrc,
                                           inn, outn, rs, hsA, E, nbuk, N);

    // L1: hsA->hsB ; L2: hsB->hsA ; L3: hsA->(pred d_out), hs_out unused
    const unsigned short* ins[3]  = {hsA, hsB, hsA};
    unsigned short*       outs[3] = {hsB, hsA, hsB};
    for (int l = 0; l < 3; ++l) {
        gcn_kernel<<<1024, 256, 0, stream>>>(
            rowptr, esrc, inn, rs, outn, ins[l],
            conv_W + (size_t)l * DD * DD, conv_b + (size_t)l * DD,
            res_W  + (size_t)l * DD * DD, res_b  + (size_t)l * DD,
            pred_W, pred_b,
            ln_g   + (size_t)l * DD,      ln_b   + (size_t)l * DD,
            outs[l], hfin, (float*)d_out, wctr + l,
            (l == 0) ? 1 : 0, (l == 2) ? 1 : 0, N);
    }
}

// Round 8
// 343.648 us; speedup vs baseline: 1.6135x; 1.6135x over previous
//
#include <hip/hip_runtime.h>
#include <hip/hip_bf16.h>

#define DD 64
#define NBLK 128          // partition pass blocks (each owns a contiguous edge chunk)
#define MAXBUK 1024       // max buckets => supports n <= 131072 (problem: n = 100000)
#define BSHIFT 7          // 128 nodes per bucket

typedef __attribute__((ext_vector_type(8))) short short8v;  // 8 bf16 MFMA A/B frag
typedef __attribute__((ext_vector_type(4))) float f32x4;    // MFMA C/D frag

__device__ __forceinline__ unsigned pk_bf16(float a, float b) {
    __hip_bfloat162 h = __float22bfloat162_rn(make_float2(a, b));
    unsigned u; __builtin_memcpy(&u, &h, 4); return u;
}
__device__ __forceinline__ short f2bf_s(float f) {   // RNE scalar (startup only)
    union { float f; unsigned u; } x; x.f = f;
    unsigned r = x.u + 0x7fff + ((x.u >> 16) & 1);
    return (short)(r >> 16);
}
__device__ __forceinline__ float bf_lo(unsigned u) { return __int_as_float(u << 16); }
__device__ __forceinline__ float bf_hi(unsigned u) { return __int_as_float(u & 0xffff0000u); }
__device__ __forceinline__ short8v u4_to_s8(uint4 u) {
    union { uint4 u; short8v s; } x; x.u = u; return x.s;
}
// 2-phase scan: final offset = blockwise-exclusive + block base (no scan3 pass)
__device__ __forceinline__ int ofs_at(const int* __restrict__ c,
                                      const int* __restrict__ bs, int i) {
    return c[i] + bs[i >> 8];
}

// =====================================================================
// CSR build, original node space — zero global atomics, 5 dispatches.
// (R7 build kept: fused scale. R8: gcn back to static schedule —
//  stealing can't beat ceil(6250/4096)=2 rounds and its same-line
//  atomics serialized — with interleaved-halves gather for 2x MLP.)
// =====================================================================

__global__ __launch_bounds__(256) void part_count(
        const int* __restrict__ src, const int* __restrict__ dst,
        int* __restrict__ cnt, int E, int nbuk, int ce) {
    __shared__ int hd[MAXBUK], hs[MAXBUK];
    for (int i = threadIdx.x; i < MAXBUK; i += 256) { hd[i] = 0; hs[i] = 0; }
    __syncthreads();
    int e0 = blockIdx.x * ce;
    int e1 = min(e0 + ce, E);
    for (int e = e0 + (int)threadIdx.x; e < e1; e += 256) {
        atomicAdd(&hd[dst[e] >> BSHIFT], 1);
        atomicAdd(&hs[src[e] >> BSHIFT], 1);
    }
    __syncthreads();
    int L2 = nbuk * NBLK;
    // [bucket][block] layout -> flat exclusive scan yields global offsets
    for (int b = threadIdx.x; b < nbuk; b += 256) {
        cnt[b * NBLK + blockIdx.x]      = hd[b];
        cnt[L2 + b * NBLK + blockIdx.x] = hs[b];
    }
}

__global__ void scan1p(int* __restrict__ a, int* __restrict__ bsums, int L) {
    __shared__ int tmp[256];
    int gid = blockIdx.x * 256 + threadIdx.x;
    int v = (gid < L) ? a[gid] : 0;
    tmp[threadIdx.x] = v;
    __syncthreads();
    for (int off = 1; off < 256; off <<= 1) {
        int t = (threadIdx.x >= off) ? tmp[threadIdx.x - off] : 0;
        __syncthreads();
        tmp[threadIdx.x] += t;
        __syncthreads();
    }
    if (gid < L) a[gid] = tmp[threadIdx.x] - v;
    if (threadIdx.x == 255) bsums[blockIdx.x] = tmp[255];
}
__global__ void scan2p(int* __restrict__ bsums, int nb) {
    __shared__ int tmp[1024];
    int v = (threadIdx.x < (unsigned)nb) ? bsums[threadIdx.x] : 0;
    tmp[threadIdx.x] = v;
    __syncthreads();
    for (int off = 1; off < 1024; off <<= 1) {
        int t = (threadIdx.x >= off) ? tmp[threadIdx.x - off] : 0;
        __syncthreads();
        tmp[threadIdx.x] += t;
        __syncthreads();
    }
    if (threadIdx.x < (unsigned)nb) bsums[threadIdx.x] = tmp[threadIdx.x] - v;
}

__global__ __launch_bounds__(256) void part_scatter(
        const int* __restrict__ src, const int* __restrict__ dst,
        const int* __restrict__ cnt, const int* __restrict__ bsA,
        unsigned int* __restrict__ partD, unsigned char* __restrict__ partS,
        int E, int nbuk, int ce) {
    __shared__ int cd[MAXBUK], cs[MAXBUK];
    int L2 = nbuk * NBLK;
    for (int b = threadIdx.x; b < nbuk; b += 256) {
        cd[b] = ofs_at(cnt, bsA, b * NBLK + blockIdx.x);
        cs[b] = ofs_at(cnt, bsA, L2 + b * NBLK + blockIdx.x) - E;
    }
    __syncthreads();
    int e0 = blockIdx.x * ce;
    int e1 = min(e0 + ce, E);
    for (int e = e0 + (int)threadIdx.x; e < e1; e += 256) {
        int s = src[e], d = dst[e];
        int pd = atomicAdd(&cd[d >> BSHIFT], 1);
        partD[pd] = ((unsigned)(d & 127) << 17) | (unsigned)s;
        int ps = atomicAdd(&cs[s >> BSHIFT], 1);
        partS[ps] = (unsigned char)(s & 127);
    }
}

// ---- fused per-bucket finalize: in-hist -> rowptr/inn + esrc scatter,
//      out-hist -> outn/rs, AND hs = feats*outn (scale fused). ----
__global__ __launch_bounds__(256) void bucket_all(
        const unsigned int* __restrict__ partD, const unsigned char* __restrict__ partS,
        const int* __restrict__ cnt, const int* __restrict__ bsA,
        const float* __restrict__ feats,
        int* __restrict__ rowptr, int* __restrict__ esrc,
        float* __restrict__ inn, float* __restrict__ outn, float* __restrict__ rs,
        unsigned short* __restrict__ hsv,
        int E, int nbuk, int n) {
    __shared__ int hi[128], sc[128], cu[128], ho[128];
    __shared__ float son[128];
    int b = blockIdx.x, tid = threadIdx.x;
    int L2 = nbuk * NBLK;
    int e0 = ofs_at(cnt, bsA, b * NBLK);
    int e1 = (b + 1 < nbuk) ? ofs_at(cnt, bsA, (b + 1) * NBLK) : E;
    int f0 = ofs_at(cnt, bsA, L2 + b * NBLK) - E;
    int f1 = (b + 1 < nbuk) ? ofs_at(cnt, bsA, L2 + (b + 1) * NBLK) - E : E;
    if (tid < 128) { hi[tid] = 0; ho[tid] = 0; }
    __syncthreads();
    for (int e = e0 + tid; e < e1; e += 256) atomicAdd(&hi[partD[e] >> 17], 1);
    for (int e = f0 + tid; e < f1; e += 256) atomicAdd(&ho[(int)partS[e]], 1);
    __syncthreads();
    if (tid < 128) sc[tid] = hi[tid];
    __syncthreads();
    for (int off = 1; off < 128; off <<= 1) {
        int t = (tid < 128 && tid >= off) ? sc[tid - off] : 0;
        __syncthreads();
        if (tid < 128) sc[tid] += t;
        __syncthreads();
    }
    int nodeBase = b << BSHIFT;
    if (tid < 128) {
        int excl = e0 + sc[tid] - hi[tid];
        cu[tid] = excl;
        float oc = (float)max(ho[tid], 1);
        float on = rsqrtf(oc);
        son[tid] = on;
        int v = nodeBase + tid;
        if (v < n) {
            rowptr[v] = excl;
            inn[v] = rsqrtf((float)max(hi[tid], 1));
            outn[v] = on;
            rs[v]   = sqrtf(oc);
        }
    }
    if (b == 0 && tid == 0) rowptr[n] = E;
    __syncthreads();
    // esrc scatter
    for (int e = e0 + tid; e < e1; e += 256) {
        unsigned u = partD[e];
        int p = atomicAdd(&cu[u >> 17], 1);
        esrc[p] = (int)(u & 0x1FFFFu);
    }
    // fused scale: hs[v] = bf16(feats[v] * outn[v]) for the 128 bucket nodes
    for (int idx = tid; idx < 128 * 8; idx += 256) {
        int vl = idx >> 3, c = idx & 7;
        int v = nodeBase + vl;
        if (v < n) {
            float s = son[vl];
            const float4* fp = (const float4*)(feats + (size_t)v * DD) + c * 2;
            float4 g0 = fp[0], g1 = fp[1];
            uint4 o;
            o.x = pk_bf16(g0.x * s, g0.y * s); o.y = pk_bf16(g0.z * s, g0.w * s);
            o.z = pk_bf16(g1.x * s, g1.y * s); o.w = pk_bf16(g1.z * s, g1.w * s);
            *(uint4*)&hsv[(size_t)v * DD + c * 8] = o;
        }
    }
}

// ---------------- fused per-layer kernel: static schedule + interleaved
// two-half gather (8 row loads in flight = 2x memory-level parallelism;
// self-row loads deferred to post-gather to keep VGPR <= 128 cliff). ------
__global__ __launch_bounds__(256) void gcn_kernel(
    const int* __restrict__ rowptr, const int* __restrict__ esrc,
    const float* __restrict__ inn, const float* __restrict__ rs,
    const float* __restrict__ outn,
    const unsigned short* __restrict__ hs_in,
    const float* __restrict__ Wc, const float* __restrict__ bc,
    const float* __restrict__ Wr, const float* __restrict__ br,
    const float* __restrict__ Wp, const float* __restrict__ pb,
    const float* __restrict__ g, const float* __restrict__ bb,
    unsigned short* __restrict__ hs_out, float* __restrict__ h_final,
    float* __restrict__ pred_out,
    int first, int last, int n)
{
    __shared__ __align__(16) short sWf[24 * 64 * 8];  // 24 A-frags (Wc|Wr|Wp) x 64 lanes x 8 bf16
    __shared__ __align__(16) short sXa[4][16 * 72];   // per-wave 16-node bf16 rows (72-short pad)
    __shared__ float sEps[4 * 64];                    // bias | ln_g | ln_b | pred_b

    int lane = threadIdx.x & 63;
    int wave = threadIdx.x >> 6;        // 0..3
    int q   = lane & 15;                // mfma: node id
    int gg  = lane >> 4;                // mfma: k/feat quad
    int q8  = lane & 7;                 // gather: 16B chunk (feats q8*8..+7)
    int o8  = lane >> 3;                // gather: node-in-half 0..7

    for (int idx = threadIdx.x; idx < 64; idx += blockDim.x) {
        sEps[idx]       = bc[idx] + br[idx];
        sEps[64 + idx]  = g[idx];
        sEps[128 + idx] = bb[idx];
        sEps[192 + idx] = pb[idx];
    }
    // A-frags: f = mat*8 + ft*2 + kc ; elem j = W[kc*32+gg*8+j][ft*16+q]
    for (int f = wave * 6; f < wave * 6 + 6; ++f) {
        int mat = f >> 3, ft = (f >> 1) & 3, kc = f & 1;
        const float* Ws = (mat == 0) ? Wc : (mat == 1) ? Wr : Wp;
        int feat = ft * 16 + q;
        int k0 = kc * 32 + gg * 8;
        short8v fr;
        #pragma unroll
        for (int j = 0; j < 8; ++j) fr[j] = f2bf_s(Ws[(k0 + j) * DD + feat]);
        *(short8v*)&sWf[(f * 64 + lane) * 8] = fr;
    }
    __syncthreads();

    short* xrow_w = &sXa[wave][0];
    const short8v* wf = (const short8v*)sWf;
    int wgid = blockIdx.x * 4 + wave;
    int nwav = gridDim.x * 4;
    int ngrp = (n + 15) >> 4;

    for (int grp = wgid; grp < ngrp; grp += nwav) {
        int vbase = grp << 4;
        int vo = vbase + q;
        int vsel = min(vo, n - 1);

        // rowptr for the 16 nodes; per-lane start/deg for both halves
        int rp = rowptr[min(vbase + min(lane, 16), n)];
        int stA = __shfl(rp, o8);     int dgA = __shfl(rp, o8 + 1) - stA;
        int stB = __shfl(rp, o8 + 8); int dgB = __shfl(rp, o8 + 9) - stB;

        // wave-uniform max degree over all 16 nodes (interleaved halves)
        int md = max(dgA, dgB);
        md = max(md, __shfl_xor(md, 8));
        md = max(md, __shfl_xor(md, 16));
        md = max(md, __shfl_xor(md, 32));

        float aA[8], aB[8];
        #pragma unroll
        for (int c = 0; c < 8; ++c) { aA[c] = 0.0f; aB[c] = 0.0f; }

        int iA0 = (0 < dgA) ? esrc[stA + 0] : 0;  float mA0 = (0 < dgA) ? 1.f : 0.f;
        int iA1 = (1 < dgA) ? esrc[stA + 1] : 0;  float mA1 = (1 < dgA) ? 1.f : 0.f;
        int iA2 = (2 < dgA) ? esrc[stA + 2] : 0;  float mA2 = (2 < dgA) ? 1.f : 0.f;
        int iA3 = (3 < dgA) ? esrc[stA + 3] : 0;  float mA3 = (3 < dgA) ? 1.f : 0.f;
        int iB0 = (0 < dgB) ? esrc[stB + 0] : 0;  float mB0 = (0 < dgB) ? 1.f : 0.f;
        int iB1 = (1 < dgB) ? esrc[stB + 1] : 0;  float mB1 = (1 < dgB) ? 1.f : 0.f;
        int iB2 = (2 < dgB) ? esrc[stB + 2] : 0;  float mB2 = (2 < dgB) ? 1.f : 0.f;
        int iB3 = (3 < dgB) ? esrc[stB + 3] : 0;  float mB3 = (3 < dgB) ? 1.f : 0.f;

        for (int t = 0; t < md; t += 4) {
            // 8 independent 16B row-chunk loads in flight (2x MLP vs seq halves)
            uint4 rA0 = *(const uint4*)(hs_in + (size_t)iA0 * DD + q8 * 8);
            uint4 rA1 = *(const uint4*)(hs_in + (size_t)iA1 * DD + q8 * 8);
            uint4 rA2 = *(const uint4*)(hs_in + (size_t)iA2 * DD + q8 * 8);
            uint4 rA3 = *(const uint4*)(hs_in + (size_t)iA3 * DD + q8 * 8);
            uint4 rB0 = *(const uint4*)(hs_in + (size_t)iB0 * DD + q8 * 8);
            uint4 rB1 = *(const uint4*)(hs_in + (size_t)iB1 * DD + q8 * 8);
            uint4 rB2 = *(const uint4*)(hs_in + (size_t)iB2 * DD + q8 * 8);
            uint4 rB3 = *(const uint4*)(hs_in + (size_t)iB3 * DD + q8 * 8);
            float cA0 = mA0, cA1 = mA1, cA2 = mA2, cA3 = mA3;
            float cB0 = mB0, cB1 = mB1, cB2 = mB2, cB3 = mB3;
            int t4 = t + 4;
            iA0 = (t4 + 0 < dgA) ? esrc[stA + t4 + 0] : 0;  mA0 = (t4 + 0 < dgA) ? 1.f : 0.f;
            iA1 = (t4 + 1 < dgA) ? esrc[stA + t4 + 1] : 0;  mA1 = (t4 + 1 < dgA) ? 1.f : 0.f;
            iA2 = (t4 + 2 < dgA) ? esrc[stA + t4 + 2] : 0;  mA2 = (t4 + 2 < dgA) ? 1.f : 0.f;
            iA3 = (t4 + 3 < dgA) ? esrc[stA + t4 + 3] : 0;  mA3 = (t4 + 3 < dgA) ? 1.f : 0.f;
            iB0 = (t4 + 0 < dgB) ? esrc[stB + t4 + 0] : 0;  mB0 = (t4 + 0 < dgB) ? 1.f : 0.f;
            iB1 = (t4 + 1 < dgB) ? esrc[stB + t4 + 1] : 0;  mB1 = (t4 + 1 < dgB) ? 1.f : 0.f;
            iB2 = (t4 + 2 < dgB) ? esrc[stB + t4 + 2] : 0;  mB2 = (t4 + 2 < dgB) ? 1.f : 0.f;
            iB3 = (t4 + 3 < dgB) ? esrc[stB + t4 + 3] : 0;  mB3 = (t4 + 3 < dgB) ? 1.f : 0.f;

            aA[0] = fmaf(bf_lo(rA0.x), cA0, aA[0]); aA[1] = fmaf(bf_hi(rA0.x), cA0, aA[1]);
            aA[2] = fmaf(bf_lo(rA0.y), cA0, aA[2]); aA[3] = fmaf(bf_hi(rA0.y), cA0, aA[3]);
            aA[4] = fmaf(bf_lo(rA0.z), cA0, aA[4]); aA[5] = fmaf(bf_hi(rA0.z), cA0, aA[5]);
            aA[6] = fmaf(bf_lo(rA0.w), cA0, aA[6]); aA[7] = fmaf(bf_hi(rA0.w), cA0, aA[7]);
            aA[0] = fmaf(bf_lo(rA1.x), cA1, aA[0]); aA[1] = fmaf(bf_hi(rA1.x), cA1, aA[1]);
            aA[2] = fmaf(bf_lo(rA1.y), cA1, aA[2]); aA[3] = fmaf(bf_hi(rA1.y), cA1, aA[3]);
            aA[4] = fmaf(bf_lo(rA1.z), cA1, aA[4]); aA[5] = fmaf(bf_hi(rA1.z), cA1, aA[5]);
            aA[6] = fmaf(bf_lo(rA1.w), cA1, aA[6]); aA[7] = fmaf(bf_hi(rA1.w), cA1, aA[7]);
            aA[0] = fmaf(bf_lo(rA2.x), cA2, aA[0]); aA[1] = fmaf(bf_hi(rA2.x), cA2, aA[1]);
            aA[2] = fmaf(bf_lo(rA2.y), cA2, aA[2]); aA[3] = fmaf(bf_hi(rA2.y), cA2, aA[3]);
            aA[4] = fmaf(bf_lo(rA2.z), cA2, aA[4]); aA[5] = fmaf(bf_hi(rA2.z), cA2, aA[5]);
            aA[6] = fmaf(bf_lo(rA2.w), cA2, aA[6]); aA[7] = fmaf(bf_hi(rA2.w), cA2, aA[7]);
            aA[0] = fmaf(bf_lo(rA3.x), cA3, aA[0]); aA[1] = fmaf(bf_hi(rA3.x), cA3, aA[1]);
            aA[2] = fmaf(bf_lo(rA3.y), cA3, aA[2]); aA[3] = fmaf(bf_hi(rA3.y), cA3, aA[3]);
            aA[4] = fmaf(bf_lo(rA3.z), cA3, aA[4]); aA[5] = fmaf(bf_hi(rA3.z), cA3, aA[5]);
            aA[6] = fmaf(bf_lo(rA3.w), cA3, aA[6]); aA[7] = fmaf(bf_hi(rA3.w), cA3, aA[7]);

            aB[0] = fmaf(bf_lo(rB0.x), cB0, aB[0]); aB[1] = fmaf(bf_hi(rB0.x), cB0, aB[1]);
            aB[2] = fmaf(bf_lo(rB0.y), cB0, aB[2]); aB[3] = fmaf(bf_hi(rB0.y), cB0, aB[3]);
            aB[4] = fmaf(bf_lo(rB0.z), cB0, aB[4]); aB[5] = fmaf(bf_hi(rB0.z), cB0, aB[5]);
            aB[6] = fmaf(bf_lo(rB0.w), cB0, aB[6]); aB[7] = fmaf(bf_hi(rB0.w), cB0, aB[7]);
            aB[0] = fmaf(bf_lo(rB1.x), cB1, aB[0]); aB[1] = fmaf(bf_hi(rB1.x), cB1, aB[1]);
            aB[2] = fmaf(bf_lo(rB1.y), cB1, aB[2]); aB[3] = fmaf(bf_hi(rB1.y), cB1, aB[3]);
            aB[4] = fmaf(bf_lo(rB1.z), cB1, aB[4]); aB[5] = fmaf(bf_hi(rB1.z), cB1, aB[5]);
            aB[6] = fmaf(bf_lo(rB1.w), cB1, aB[6]); aB[7] = fmaf(bf_hi(rB1.w), cB1, aB[7]);
            aB[0] = fmaf(bf_lo(rB2.x), cB2, aB[0]); aB[1] = fmaf(bf_hi(rB2.x), cB2, aB[1]);
            aB[2] = fmaf(bf_lo(rB2.y), cB2, aB[2]); aB[3] = fmaf(bf_hi(rB2.y), cB2, aB[3]);
            aB[4] = fmaf(bf_lo(rB2.z), cB2, aB[4]); aB[5] = fmaf(bf_hi(rB2.z), cB2, aB[5]);
            aB[6] = fmaf(bf_lo(rB2.w), cB2, aB[6]); aB[7] = fmaf(bf_hi(rB2.w), cB2, aB[7]);
            aB[0] = fmaf(bf_lo(rB3.x), cB3, aB[0]); aB[1] = fmaf(bf_hi(rB3.x), cB3, aB[1]);
            aB[2] = fmaf(bf_lo(rB3.y), cB3, aB[2]); aB[3] = fmaf(bf_hi(rB3.y), cB3, aB[3]);
            aB[4] = fmaf(bf_lo(rB3.z), cB3, aB[4]); aB[5] = fmaf(bf_hi(rB3.z), cB3, aB[5]);
            aB[6] = fmaf(bf_lo(rB3.w), cB3, aB[6]); aB[7] = fmaf(bf_hi(rB3.w), cB3, aB[7]);
        }

        // self row B-frags + norms (deferred: frees regs during gather;
        // latency hides under LDS pack + conv MFMAs below)
        const uint4* hrow = (const uint4*)(hs_in + (size_t)vsel * DD);
        uint4 bh0u = hrow[gg];
        uint4 bh1u = hrow[4 + gg];
        float rsv  = rs[vsel];
        float innv = inn[vsel];

        // pack + LDS write (both halves)
        uint4 w4;
        w4.x = pk_bf16(aA[0], aA[1]); w4.y = pk_bf16(aA[2], aA[3]);
        w4.z = pk_bf16(aA[4], aA[5]); w4.w = pk_bf16(aA[6], aA[7]);
        *(uint4*)&xrow_w[o8 * 72 + q8 * 8] = w4;
        w4.x = pk_bf16(aB[0], aB[1]); w4.y = pk_bf16(aB[2], aB[3]);
        w4.z = pk_bf16(aB[4], aB[5]); w4.w = pk_bf16(aB[6], aB[7]);
        *(uint4*)&xrow_w[(8 + o8) * 72 + q8 * 8] = w4;

        // ---- B-frags + 16 MFMA (separate conv/res accumulators) ----
        const short* xr = &xrow_w[q * 72];
        short8v ba0 = *(const short8v*)&xr[gg * 8];
        short8v ba1 = *(const short8v*)&xr[32 + gg * 8];

        f32x4 accC[4], accR[4];
        #pragma unroll
        for (int ft = 0; ft < 4; ++ft) {
            f32x4 c = {0.f, 0.f, 0.f, 0.f};
            c = __builtin_amdgcn_mfma_f32_16x16x32_bf16(wf[(ft * 2 + 0) * 64 + lane], ba0, c, 0, 0, 0);
            c = __builtin_amdgcn_mfma_f32_16x16x32_bf16(wf[(ft * 2 + 1) * 64 + lane], ba1, c, 0, 0, 0);
            accC[ft] = c;
        }
        short8v sh0 = u4_to_s8(bh0u);
        short8v sh1 = u4_to_s8(bh1u);
        #pragma unroll
        for (int ft = 0; ft < 4; ++ft) {
            f32x4 r = {0.f, 0.f, 0.f, 0.f};
            r = __builtin_amdgcn_mfma_f32_16x16x32_bf16(wf[(8 + ft * 2 + 0) * 64 + lane], sh0, r, 0, 0, 0);
            r = __builtin_amdgcn_mfma_f32_16x16x32_bf16(wf[(8 + ft * 2 + 1) * 64 + lane], sh1, r, 0, 0, 0);
            accR[ft] = r;
        }

        // ---- combine (inn*conv + rs*res + bias) + LayerNorm + relu ----
        f32x4 ac[4];
        #pragma unroll
        for (int ft = 0; ft < 4; ++ft) {
            float4 b4 = *(const float4*)&sEps[ft * 16 + gg * 4];
            ac[ft][0] = fmaf(innv, accC[ft][0], fmaf(rsv, accR[ft][0], b4.x));
            ac[ft][1] = fmaf(innv, accC[ft][1], fmaf(rsv, accR[ft][1], b4.y));
            ac[ft][2] = fmaf(innv, accC[ft][2], fmaf(rsv, accR[ft][2], b4.z));
            ac[ft][3] = fmaf(innv, accC[ft][3], fmaf(rsv, accR[ft][3], b4.w));
        }
        float s = 0.f;
        #pragma unroll
        for (int ft = 0; ft < 4; ++ft) s += ac[ft][0] + ac[ft][1] + ac[ft][2] + ac[ft][3];
        s += __shfl_xor(s, 16); s += __shfl_xor(s, 32);
        float mu = s * (1.0f / 64.0f);
        float vsum = 0.f;
        #pragma unroll
        for (int ft = 0; ft < 4; ++ft) {
            #pragma unroll
            for (int r = 0; r < 4; ++r) { float d = ac[ft][r] - mu; vsum += d * d; }
        }
        vsum += __shfl_xor(vsum, 16); vsum += __shfl_xor(vsum, 32);
        float rinv = rsqrtf(vsum * (1.0f / 64.0f) + 1e-5f);

        float4 yv[4];
        #pragma unroll
        for (int ft = 0; ft < 4; ++ft) {
            float4 g4 = *(const float4*)&sEps[64 + ft * 16 + gg * 4];
            float4 c4 = *(const float4*)&sEps[128 + ft * 16 + gg * 4];
            yv[ft].x = fmaxf((ac[ft][0] - mu) * rinv * g4.x + c4.x, 0.f);
            yv[ft].y = fmaxf((ac[ft][1] - mu) * rinv * g4.y + c4.y, 0.f);
            yv[ft].z = fmaxf((ac[ft][2] - mu) * rinv * g4.z + c4.z, 0.f);
            yv[ft].w = fmaxf((ac[ft][3] - mu) * rinv * g4.w + c4.w, 0.f);
        }

        if (!last) {
            if (vo < n) {
                float on = outn[vo];
                #pragma unroll
                for (int ft = 0; ft < 4; ++ft) {
                    size_t off = (size_t)vo * DD + ft * 16 + gg * 4;
                    uint2 p;
                    p.x = pk_bf16(yv[ft].x * on, yv[ft].y * on);
                    p.y = pk_bf16(yv[ft].z * on, yv[ft].w * on);
                    *(uint2*)&hs_out[off] = p;
                    if (first) {
                        *(float4*)&h_final[off] = yv[ft];
                    } else {
                        float4 hf = *(const float4*)&h_final[off];
                        hf.x += yv[ft].x; hf.y += yv[ft].y;
                        hf.z += yv[ft].z; hf.w += yv[ft].w;
                        *(float4*)&h_final[off] = hf;
                    }
                }
            }
        } else {
            // fused prediction: hf = h_final + y -> LDS (bf16) -> B-frags -> 8 MFMA -> d_out
            #pragma unroll
            for (int ft = 0; ft < 4; ++ft) {
                float4 hf = make_float4(0.f, 0.f, 0.f, 0.f);
                if (vo < n) {
                    float4 old = *(const float4*)&h_final[(size_t)vo * DD + ft * 16 + gg * 4];
                    hf.x = old.x + yv[ft].x; hf.y = old.y + yv[ft].y;
                    hf.z = old.z + yv[ft].z; hf.w = old.w + yv[ft].w;
                }
                uint2 p;
                p.x = pk_bf16(hf.x, hf.y);
                p.y = pk_bf16(hf.z, hf.w);
                *(uint2*)&xrow_w[q * 72 + ft * 16 + gg * 4] = p;   // same-wave DS, in order
            }
            short8v bp0 = *(const short8v*)&xr[gg * 8];
            short8v bp1 = *(const short8v*)&xr[32 + gg * 8];
            #pragma unroll
            for (int ft = 0; ft < 4; ++ft) {
                f32x4 p = {0.f, 0.f, 0.f, 0.f};
                p = __builtin_amdgcn_mfma_f32_16x16x32_bf16(wf[(16 + ft * 2 + 0) * 64 + lane], bp0, p, 0, 0, 0);
                p = __builtin_amdgcn_mfma_f32_16x16x32_bf16(wf[(16 + ft * 2 + 1) * 64 + lane], bp1, p, 0, 0, 0);
                if (vo < n) {
                    float4 b4 = *(const float4*)&sEps[192 + ft * 16 + gg * 4];
                    float4 o = make_float4(p[0] + b4.x, p[1] + b4.y, p[2] + b4.z, p[3] + b4.w);
                    *(float4*)&pred_out[(size_t)vo * DD + ft * 16 + gg * 4] = o;
                }
            }
        }
    }
}

extern "C" void kernel_launch(void* const* d_in, const int* in_sizes, int n_in,
                              void* d_out, int out_size, void* d_ws, size_t ws_size,
                              hipStream_t stream) {
    const float* feats  = (const float*)d_in[0];
    const int*   src    = (const int*)d_in[1];
    const int*   dst    = (const int*)d_in[2];
    const float* conv_W = (const float*)d_in[3];
    const float* conv_b = (const float*)d_in[4];
    const float* res_W  = (const float*)d_in[5];
    const float* res_b  = (const float*)d_in[6];
    const float* ln_g   = (const float*)d_in[7];
    const float* ln_b   = (const float*)d_in[8];
    const float* pred_W = (const float*)d_in[9];
    const float* pred_b = (const float*)d_in[10];

    int N = in_sizes[0] / DD;
    int E = in_sizes[1];

    int nbuk = (N + (1 << BSHIFT) - 1) >> BSHIFT;        // 782
    int ce   = (E + NBLK - 1) / NBLK;
    int L    = nbuk * NBLK * 2;                          // 200192
    int nb   = (L + 255) / 256;                          // 783 (<=1024 for scan2p)

    // ---- workspace layout (~58 MB) ----
    int*   rowptr = (int*)d_ws;                          // N+1
    int*   cnt    = rowptr + (N + 1);                    // MAXBUK*NBLK*2 (1 MB)
    int*   bsA    = cnt + MAXBUK * NBLK * 2;             // 1024
    int*   esrc   = bsA + 1024;                          // E
    float* outn   = (float*)(esrc + E);                  // N
    float* inn    = outn + N;                            // N
    float* rs     = inn + N;                             // N
    float* base   = (float*)(((uintptr_t)(rs + N) + 15) & ~(uintptr_t)15);
    unsigned short* hsA = (unsigned short*)base;                     // N*64 bf16
    unsigned short* hsB = (unsigned short*)(base + (size_t)N * 32);  // N*64 bf16
    float* hfin  = base + (size_t)N * 64;                // N*64 fp32
    // partition scratch aliases hfin (dead before layer-0 writes hfin)
    unsigned int*  partD = (unsigned int*)hfin;                      // E uints
    unsigned char* partS = (unsigned char*)(partD + E);              // E bytes

    part_count  <<<NBLK, 256, 0, stream>>>(src, dst, cnt, E, nbuk, ce);
    scan1p      <<<nb, 256, 0, stream>>>(cnt, bsA, L);
    scan2p      <<<1, 1024, 0, stream>>>(bsA, nb);
    part_scatter<<<NBLK, 256, 0, stream>>>(src, dst, cnt, bsA, partD, partS, E, nbuk, ce);
    bucket_all  <<<nbuk, 256, 0, stream>>>(partD, partS, cnt, bsA, feats, rowptr, esrc,
                                           inn, outn, rs, hsA, E, nbuk, N);

    // L1: hsA->hsB ; L2: hsB->hsA ; L3: hsA->(pred d_out), hs_out unused
    const unsigned short* ins[3]  = {hsA, hsB, hsA};
    unsigned short*       outs[3] = {hsB, hsA, hsB};
    for (int l = 0; l < 3; ++l) {
        gcn_kernel<<<1024, 256, 0, stream>>>(
            rowptr, esrc, inn, rs, outn, ins[l],
            conv_W + (size_t)l * DD * DD, conv_b + (size_t)l * DD,
            res_W  + (size_t)l * DD * DD, res_b  + (size_t)l * DD,
            pred_W, pred_b,
            ln_g   + (size_t)l * DD,      ln_b   + (size_t)l * DD,
            outs[l], hfin, (float*)d_out,
            (l == 0) ? 1 : 0, (l == 2) ? 1 : 0, N);
    }
}

// Round 9
// 291.158 us; speedup vs baseline: 1.9044x; 1.1803x over previous
//
#include <hip/hip_runtime.h>
#include <hip/hip_bf16.h>

#define DD 64
#define NBLK 128          // partition pass blocks (each owns a contiguous edge chunk)
#define MAXBUK 1024       // max buckets => supports n <= 131072 (problem: n = 100000)
#define BSHIFT 7          // 128 nodes per bucket
#define NCTR 64           // steal counters per layer (separate 128B lines)

typedef __attribute__((ext_vector_type(8))) short short8v;  // 8 bf16 MFMA A/B frag
typedef __attribute__((ext_vector_type(4))) float f32x4;    // MFMA C/D frag

__device__ __forceinline__ unsigned pk_bf16(float a, float b) {
    __hip_bfloat162 h = __float22bfloat162_rn(make_float2(a, b));
    unsigned u; __builtin_memcpy(&u, &h, 4); return u;
}
__device__ __forceinline__ short f2bf_s(float f) {   // RNE scalar (startup only)
    union { float f; unsigned u; } x; x.f = f;
    unsigned r = x.u + 0x7fff + ((x.u >> 16) & 1);
    return (short)(r >> 16);
}
__device__ __forceinline__ float bf_lo(unsigned u) { return __int_as_float(u << 16); }
__device__ __forceinline__ float bf_hi(unsigned u) { return __int_as_float(u & 0xffff0000u); }
__device__ __forceinline__ short8v u4_to_s8(uint4 u) {
    union { uint4 u; short8v s; } x; x.u = u; return x.s;
}
// 2-phase scan: final offset = blockwise-exclusive + block base (no scan3 pass)
__device__ __forceinline__ int ofs_at(const int* __restrict__ c,
                                      const int* __restrict__ bs, int i) {
    return c[i] + bs[i >> 8];
}

// =====================================================================
// CSR build, original node space — zero global atomics, 5 dispatches.
// R9: R6 gcn body (116 VGPR, verified 55.5us) + distributed 64-line
// steal counters. R7 lesson: SAME-LINE device atomics serialize at
// ~15-30ns each (6250 on one line = ~100us); 64 lines -> ~3us, hidden.
// R8 lesson: interleaved-halves gather needs VGPR>128 -> occupancy cliff.
// =====================================================================

__global__ __launch_bounds__(256) void part_count(
        const int* __restrict__ src, const int* __restrict__ dst,
        int* __restrict__ cnt, int* __restrict__ wctr, int E, int nbuk, int ce,
        int chunk) {
    __shared__ int hd[MAXBUK], hs[MAXBUK];
    // seed 3 layer-banks of 64 steal counters, each on its own 128B line
    if (blockIdx.x == 0) {
        for (int i = threadIdx.x; i < 3 * NCTR; i += 256)
            wctr[i * 32] = (i & (NCTR - 1)) * chunk;
    }
    for (int i = threadIdx.x; i < MAXBUK; i += 256) { hd[i] = 0; hs[i] = 0; }
    __syncthreads();
    int e0 = blockIdx.x * ce;
    int e1 = min(e0 + ce, E);
    for (int e = e0 + (int)threadIdx.x; e < e1; e += 256) {
        atomicAdd(&hd[dst[e] >> BSHIFT], 1);
        atomicAdd(&hs[src[e] >> BSHIFT], 1);
    }
    __syncthreads();
    int L2 = nbuk * NBLK;
    // [bucket][block] layout -> flat exclusive scan yields global offsets
    for (int b = threadIdx.x; b < nbuk; b += 256) {
        cnt[b * NBLK + blockIdx.x]      = hd[b];
        cnt[L2 + b * NBLK + blockIdx.x] = hs[b];
    }
}

__global__ void scan1p(int* __restrict__ a, int* __restrict__ bsums, int L) {
    __shared__ int tmp[256];
    int gid = blockIdx.x * 256 + threadIdx.x;
    int v = (gid < L) ? a[gid] : 0;
    tmp[threadIdx.x] = v;
    __syncthreads();
    for (int off = 1; off < 256; off <<= 1) {
        int t = (threadIdx.x >= off) ? tmp[threadIdx.x - off] : 0;
        __syncthreads();
        tmp[threadIdx.x] += t;
        __syncthreads();
    }
    if (gid < L) a[gid] = tmp[threadIdx.x] - v;
    if (threadIdx.x == 255) bsums[blockIdx.x] = tmp[255];
}
__global__ void scan2p(int* __restrict__ bsums, int nb) {
    __shared__ int tmp[1024];
    int v = (threadIdx.x < (unsigned)nb) ? bsums[threadIdx.x] : 0;
    tmp[threadIdx.x] = v;
    __syncthreads();
    for (int off = 1; off < 1024; off <<= 1) {
        int t = (threadIdx.x >= off) ? tmp[threadIdx.x - off] : 0;
        __syncthreads();
        tmp[threadIdx.x] += t;
        __syncthreads();
    }
    if (threadIdx.x < (unsigned)nb) bsums[threadIdx.x] = tmp[threadIdx.x] - v;
}

__global__ __launch_bounds__(256) void part_scatter(
        const int* __restrict__ src, const int* __restrict__ dst,
        const int* __restrict__ cnt, const int* __restrict__ bsA,
        unsigned int* __restrict__ partD, unsigned char* __restrict__ partS,
        int E, int nbuk, int ce) {
    __shared__ int cd[MAXBUK], cs[MAXBUK];
    int L2 = nbuk * NBLK;
    for (int b = threadIdx.x; b < nbuk; b += 256) {
        cd[b] = ofs_at(cnt, bsA, b * NBLK + blockIdx.x);
        cs[b] = ofs_at(cnt, bsA, L2 + b * NBLK + blockIdx.x) - E;
    }
    __syncthreads();
    int e0 = blockIdx.x * ce;
    int e1 = min(e0 + ce, E);
    for (int e = e0 + (int)threadIdx.x; e < e1; e += 256) {
        int s = src[e], d = dst[e];
        int pd = atomicAdd(&cd[d >> BSHIFT], 1);
        partD[pd] = ((unsigned)(d & 127) << 17) | (unsigned)s;
        int ps = atomicAdd(&cs[s >> BSHIFT], 1);
        partS[ps] = (unsigned char)(s & 127);
    }
}

// ---- fused per-bucket finalize: in-hist -> rowptr/inn + esrc scatter,
//      out-hist -> outn/rs, AND hs = feats*outn (scale fused). ----
__global__ __launch_bounds__(256) void bucket_all(
        const unsigned int* __restrict__ partD, const unsigned char* __restrict__ partS,
        const int* __restrict__ cnt, const int* __restrict__ bsA,
        const float* __restrict__ feats,
        int* __restrict__ rowptr, int* __restrict__ esrc,
        float* __restrict__ inn, float* __restrict__ outn, float* __restrict__ rs,
        unsigned short* __restrict__ hsv,
        int E, int nbuk, int n) {
    __shared__ int hi[128], sc[128], cu[128], ho[128];
    __shared__ float son[128];
    int b = blockIdx.x, tid = threadIdx.x;
    int L2 = nbuk * NBLK;
    int e0 = ofs_at(cnt, bsA, b * NBLK);
    int e1 = (b + 1 < nbuk) ? ofs_at(cnt, bsA, (b + 1) * NBLK) : E;
    int f0 = ofs_at(cnt, bsA, L2 + b * NBLK) - E;
    int f1 = (b + 1 < nbuk) ? ofs_at(cnt, bsA, L2 + (b + 1) * NBLK) - E : E;
    if (tid < 128) { hi[tid] = 0; ho[tid] = 0; }
    __syncthreads();
    for (int e = e0 + tid; e < e1; e += 256) atomicAdd(&hi[partD[e] >> 17], 1);
    for (int e = f0 + tid; e < f1; e += 256) atomicAdd(&ho[(int)partS[e]], 1);
    __syncthreads();
    if (tid < 128) sc[tid] = hi[tid];
    __syncthreads();
    for (int off = 1; off < 128; off <<= 1) {
        int t = (tid < 128 && tid >= off) ? sc[tid - off] : 0;
        __syncthreads();
        if (tid < 128) sc[tid] += t;
        __syncthreads();
    }
    int nodeBase = b << BSHIFT;
    if (tid < 128) {
        int excl = e0 + sc[tid] - hi[tid];
        cu[tid] = excl;
        float oc = (float)max(ho[tid], 1);
        float on = rsqrtf(oc);
        son[tid] = on;
        int v = nodeBase + tid;
        if (v < n) {
            rowptr[v] = excl;
            inn[v] = rsqrtf((float)max(hi[tid], 1));
            outn[v] = on;
            rs[v]   = sqrtf(oc);
        }
    }
    if (b == 0 && tid == 0) rowptr[n] = E;
    __syncthreads();
    // esrc scatter
    for (int e = e0 + tid; e < e1; e += 256) {
        unsigned u = partD[e];
        int p = atomicAdd(&cu[u >> 17], 1);
        esrc[p] = (int)(u & 0x1FFFFu);
    }
    // fused scale: hs[v] = bf16(feats[v] * outn[v]) for the 128 bucket nodes
    for (int idx = tid; idx < 128 * 8; idx += 256) {
        int vl = idx >> 3, c = idx & 7;
        int v = nodeBase + vl;
        if (v < n) {
            float s = son[vl];
            const float4* fp = (const float4*)(feats + (size_t)v * DD) + c * 2;
            float4 g0 = fp[0], g1 = fp[1];
            uint4 o;
            o.x = pk_bf16(g0.x * s, g0.y * s); o.y = pk_bf16(g0.z * s, g0.w * s);
            o.z = pk_bf16(g1.x * s, g1.y * s); o.w = pk_bf16(g1.z * s, g1.w * s);
            *(uint4*)&hsv[(size_t)v * DD + c * 8] = o;
        }
    }
}

// ---------------- fused per-layer kernel: R6 body + 64-line steal -----------
__global__ __launch_bounds__(256) void gcn_kernel(
    const int* __restrict__ rowptr, const int* __restrict__ esrc,
    const float* __restrict__ inn, const float* __restrict__ rs,
    const float* __restrict__ outn,
    const unsigned short* __restrict__ hs_in,
    const float* __restrict__ Wc, const float* __restrict__ bc,
    const float* __restrict__ Wr, const float* __restrict__ br,
    const float* __restrict__ Wp, const float* __restrict__ pb,
    const float* __restrict__ g, const float* __restrict__ bb,
    unsigned short* __restrict__ hs_out, float* __restrict__ h_final,
    float* __restrict__ pred_out, int* __restrict__ wctr, int chunk,
    int first, int last, int n)
{
    __shared__ __align__(16) short sWf[24 * 64 * 8];  // 24 A-frags (Wc|Wr|Wp) x 64 lanes x 8 bf16
    __shared__ __align__(16) short sXa[4][16 * 72];   // per-wave 16-node bf16 rows (72-short pad)
    __shared__ float sEps[4 * 64];                    // bias | ln_g | ln_b | pred_b

    int lane = threadIdx.x & 63;
    int wave = threadIdx.x >> 6;        // 0..3
    int q   = lane & 15;                // mfma: node id
    int gg  = lane >> 4;                // mfma: k/feat quad
    int q8  = lane & 7;                 // gather: 16B chunk (feats q8*8..+7)
    int o8  = lane >> 3;                // gather: node-in-half 0..7

    for (int idx = threadIdx.x; idx < 64; idx += blockDim.x) {
        sEps[idx]       = bc[idx] + br[idx];
        sEps[64 + idx]  = g[idx];
        sEps[128 + idx] = bb[idx];
        sEps[192 + idx] = pb[idx];
    }
    // A-frags: f = mat*8 + ft*2 + kc ; elem j = W[kc*32+gg*8+j][ft*16+q]
    for (int f = wave * 6; f < wave * 6 + 6; ++f) {
        int mat = f >> 3, ft = (f >> 1) & 3, kc = f & 1;
        const float* Ws = (mat == 0) ? Wc : (mat == 1) ? Wr : Wp;
        int feat = ft * 16 + q;
        int k0 = kc * 32 + gg * 8;
        short8v fr;
        #pragma unroll
        for (int j = 0; j < 8; ++j) fr[j] = f2bf_s(Ws[(k0 + j) * DD + feat]);
        *(short8v*)&sWf[(f * 64 + lane) * 8] = fr;
    }
    __syncthreads();

    short* xrow_w = &sXa[wave][0];
    const short8v* wf = (const short8v*)sWf;
    int ngrp = (n + 15) >> 4;

    // distributed steal: counter c on its own 128B line; pool = groups
    // [c*chunk, min((c+1)*chunk, ngrp)). ~98 atomics/line, prefetched.
    int c = blockIdx.x & (NCTR - 1);
    int* ctr = wctr + c * 32;
    int lim = min((c + 1) * chunk, ngrp);

    int grp = 0;
    if (lane == 0) grp = atomicAdd(ctr, 1);
    grp = __shfl(grp, 0);

    while (grp < lim) {
        int gnext = 0;
        if (lane == 0) gnext = atomicAdd(ctr, 1);   // overlaps entire group body

        int vbase = grp << 4;
        int vo = vbase + q;
        int vsel = min(vo, n - 1);

        // self row B-frags (raw bf16), issued early to overlap gather
        const uint4* hrow = (const uint4*)(hs_in + (size_t)vsel * DD);
        uint4 bh0u = hrow[gg];
        uint4 bh1u = hrow[4 + gg];
        float rsv  = rs[vsel];
        float innv = inn[vsel];

        // rowptr for the 16 nodes; per-lane start/deg for both halves
        int rp = rowptr[min(vbase + min(lane, 16), n)];
        int stA = __shfl(rp, o8);     int dgA = __shfl(rp, o8 + 1) - stA;
        int stB = __shfl(rp, o8 + 8); int dgB = __shfl(rp, o8 + 9) - stB;

        #pragma unroll
        for (int hh = 0; hh < 2; ++hh) {
            int st = hh ? stB : stA;
            int dg = hh ? dgB : dgA;
            // wave-uniform max degree over this half's 8 nodes
            int mdg = dg;
            mdg = max(mdg, __shfl_xor(mdg, 8));
            mdg = max(mdg, __shfl_xor(mdg, 16));
            mdg = max(mdg, __shfl_xor(mdg, 32));

            float a[8];
            #pragma unroll
            for (int cc = 0; cc < 8; ++cc) a[cc] = 0.0f;

            int id0 = (0 < dg) ? esrc[st + 0] : 0;  float m0 = (0 < dg) ? 1.f : 0.f;
            int id1 = (1 < dg) ? esrc[st + 1] : 0;  float m1 = (1 < dg) ? 1.f : 0.f;
            int id2 = (2 < dg) ? esrc[st + 2] : 0;  float m2 = (2 < dg) ? 1.f : 0.f;
            int id3 = (3 < dg) ? esrc[st + 3] : 0;  float m3 = (3 < dg) ? 1.f : 0.f;

            for (int t = 0; t < mdg; t += 4) {
                // 4 independent 16B row-chunk loads (wave: 4 x 1KB coalesced)
                uint4 r0 = *(const uint4*)(hs_in + (size_t)id0 * DD + q8 * 8);
                uint4 r1 = *(const uint4*)(hs_in + (size_t)id1 * DD + q8 * 8);
                uint4 r2 = *(const uint4*)(hs_in + (size_t)id2 * DD + q8 * 8);
                uint4 r3 = *(const uint4*)(hs_in + (size_t)id3 * DD + q8 * 8);
                float c0 = m0, c1 = m1, c2 = m2, c3 = m3;
                // prefetch next 4 edge indices (overlap row loads)
                int t4 = t + 4;
                id0 = (t4 + 0 < dg) ? esrc[st + t4 + 0] : 0;  m0 = (t4 + 0 < dg) ? 1.f : 0.f;
                id1 = (t4 + 1 < dg) ? esrc[st + t4 + 1] : 0;  m1 = (t4 + 1 < dg) ? 1.f : 0.f;
                id2 = (t4 + 2 < dg) ? esrc[st + t4 + 2] : 0;  m2 = (t4 + 2 < dg) ? 1.f : 0.f;
                id3 = (t4 + 3 < dg) ? esrc[st + t4 + 3] : 0;  m3 = (t4 + 3 < dg) ? 1.f : 0.f;
                // accumulate
                a[0] = fmaf(bf_lo(r0.x), c0, a[0]); a[1] = fmaf(bf_hi(r0.x), c0, a[1]);
                a[2] = fmaf(bf_lo(r0.y), c0, a[2]); a[3] = fmaf(bf_hi(r0.y), c0, a[3]);
                a[4] = fmaf(bf_lo(r0.z), c0, a[4]); a[5] = fmaf(bf_hi(r0.z), c0, a[5]);
                a[6] = fmaf(bf_lo(r0.w), c0, a[6]); a[7] = fmaf(bf_hi(r0.w), c0, a[7]);
                a[0] = fmaf(bf_lo(r1.x), c1, a[0]); a[1] = fmaf(bf_hi(r1.x), c1, a[1]);
                a[2] = fmaf(bf_lo(r1.y), c1, a[2]); a[3] = fmaf(bf_hi(r1.y), c1, a[3]);
                a[4] = fmaf(bf_lo(r1.z), c1, a[4]); a[5] = fmaf(bf_hi(r1.z), c1, a[5]);
                a[6] = fmaf(bf_lo(r1.w), c1, a[6]); a[7] = fmaf(bf_hi(r1.w), c1, a[7]);
                a[0] = fmaf(bf_lo(r2.x), c2, a[0]); a[1] = fmaf(bf_hi(r2.x), c2, a[1]);
                a[2] = fmaf(bf_lo(r2.y), c2, a[2]); a[3] = fmaf(bf_hi(r2.y), c2, a[3]);
                a[4] = fmaf(bf_lo(r2.z), c2, a[4]); a[5] = fmaf(bf_hi(r2.z), c2, a[5]);
                a[6] = fmaf(bf_lo(r2.w), c2, a[6]); a[7] = fmaf(bf_hi(r2.w), c2, a[7]);
                a[0] = fmaf(bf_lo(r3.x), c3, a[0]); a[1] = fmaf(bf_hi(r3.x), c3, a[1]);
                a[2] = fmaf(bf_lo(r3.y), c3, a[2]); a[3] = fmaf(bf_hi(r3.y), c3, a[3]);
                a[4] = fmaf(bf_lo(r3.z), c3, a[4]); a[5] = fmaf(bf_hi(r3.z), c3, a[5]);
                a[6] = fmaf(bf_lo(r3.w), c3, a[6]); a[7] = fmaf(bf_hi(r3.w), c3, a[7]);
            }

            // lane holds its node-chunk's final raw sums; pack + one LDS write
            uint4 w4;
            w4.x = pk_bf16(a[0], a[1]); w4.y = pk_bf16(a[2], a[3]);
            w4.z = pk_bf16(a[4], a[5]); w4.w = pk_bf16(a[6], a[7]);
            *(uint4*)&xrow_w[(hh * 8 + o8) * 72 + q8 * 8] = w4;
        }

        // ---- B-frags + 16 MFMA (separate conv/res accumulators) ----
        const short* xr = &xrow_w[q * 72];
        short8v ba0 = *(const short8v*)&xr[gg * 8];
        short8v ba1 = *(const short8v*)&xr[32 + gg * 8];
        short8v sh0 = u4_to_s8(bh0u);
        short8v sh1 = u4_to_s8(bh1u);

        f32x4 accC[4], accR[4];
        #pragma unroll
        for (int ft = 0; ft < 4; ++ft) {
            f32x4 cq = {0.f, 0.f, 0.f, 0.f};
            cq = __builtin_amdgcn_mfma_f32_16x16x32_bf16(wf[(ft * 2 + 0) * 64 + lane], ba0, cq, 0, 0, 0);
            cq = __builtin_amdgcn_mfma_f32_16x16x32_bf16(wf[(ft * 2 + 1) * 64 + lane], ba1, cq, 0, 0, 0);
            accC[ft] = cq;
            f32x4 r = {0.f, 0.f, 0.f, 0.f};
            r = __builtin_amdgcn_mfma_f32_16x16x32_bf16(wf[(8 + ft * 2 + 0) * 64 + lane], sh0, r, 0, 0, 0);
            r = __builtin_amdgcn_mfma_f32_16x16x32_bf16(wf[(8 + ft * 2 + 1) * 64 + lane], sh1, r, 0, 0, 0);
            accR[ft] = r;
        }

        // ---- combine (inn*conv + rs*res + bias) + LayerNorm + relu ----
        f32x4 ac[4];
        #pragma unroll
        for (int ft = 0; ft < 4; ++ft) {
            float4 b4 = *(const float4*)&sEps[ft * 16 + gg * 4];
            ac[ft][0] = fmaf(innv, accC[ft][0], fmaf(rsv, accR[ft][0], b4.x));
            ac[ft][1] = fmaf(innv, accC[ft][1], fmaf(rsv, accR[ft][1], b4.y));
            ac[ft][2] = fmaf(innv, accC[ft][2], fmaf(rsv, accR[ft][2], b4.z));
            ac[ft][3] = fmaf(innv, accC[ft][3], fmaf(rsv, accR[ft][3], b4.w));
        }
        float s = 0.f;
        #pragma unroll
        for (int ft = 0; ft < 4; ++ft) s += ac[ft][0] + ac[ft][1] + ac[ft][2] + ac[ft][3];
        s += __shfl_xor(s, 16); s += __shfl_xor(s, 32);
        float mu = s * (1.0f / 64.0f);
        float vsum = 0.f;
        #pragma unroll
        for (int ft = 0; ft < 4; ++ft) {
            #pragma unroll
            for (int r = 0; r < 4; ++r) { float d = ac[ft][r] - mu; vsum += d * d; }
        }
        vsum += __shfl_xor(vsum, 16); vsum += __shfl_xor(vsum, 32);
        float rinv = rsqrtf(vsum * (1.0f / 64.0f) + 1e-5f);

        float4 yv[4];
        #pragma unroll
        for (int ft = 0; ft < 4; ++ft) {
            float4 g4 = *(const float4*)&sEps[64 + ft * 16 + gg * 4];
            float4 c4 = *(const float4*)&sEps[128 + ft * 16 + gg * 4];
            yv[ft].x = fmaxf((ac[ft][0] - mu) * rinv * g4.x + c4.x, 0.f);
            yv[ft].y = fmaxf((ac[ft][1] - mu) * rinv * g4.y + c4.y, 0.f);
            yv[ft].z = fmaxf((ac[ft][2] - mu) * rinv * g4.z + c4.z, 0.f);
            yv[ft].w = fmaxf((ac[ft][3] - mu) * rinv * g4.w + c4.w, 0.f);
        }

        if (!last) {
            if (vo < n) {
                float on = outn[vo];
                #pragma unroll
                for (int ft = 0; ft < 4; ++ft) {
                    size_t off = (size_t)vo * DD + ft * 16 + gg * 4;
                    uint2 p;
                    p.x = pk_bf16(yv[ft].x * on, yv[ft].y * on);
                    p.y = pk_bf16(yv[ft].z * on, yv[ft].w * on);
                    *(uint2*)&hs_out[off] = p;
                    if (first) {
                        *(float4*)&h_final[off] = yv[ft];
                    } else {
                        float4 hf = *(const float4*)&h_final[off];
                        hf.x += yv[ft].x; hf.y += yv[ft].y;
                        hf.z += yv[ft].z; hf.w += yv[ft].w;
                        *(float4*)&h_final[off] = hf;
                    }
                }
            }
        } else {
            // fused prediction: hf = h_final + y -> LDS (bf16) -> B-frags -> 8 MFMA -> d_out
            #pragma unroll
            for (int ft = 0; ft < 4; ++ft) {
                float4 hf = make_float4(0.f, 0.f, 0.f, 0.f);
                if (vo < n) {
                    float4 old = *(const float4*)&h_final[(size_t)vo * DD + ft * 16 + gg * 4];
                    hf.x = old.x + yv[ft].x; hf.y = old.y + yv[ft].y;
                    hf.z = old.z + yv[ft].z; hf.w = old.w + yv[ft].w;
                }
                uint2 p;
                p.x = pk_bf16(hf.x, hf.y);
                p.y = pk_bf16(hf.z, hf.w);
                *(uint2*)&xrow_w[q * 72 + ft * 16 + gg * 4] = p;   // same-wave DS, in order
            }
            short8v bp0 = *(const short8v*)&xr[gg * 8];
            short8v bp1 = *(const short8v*)&xr[32 + gg * 8];
            #pragma unroll
            for (int ft = 0; ft < 4; ++ft) {
                f32x4 p = {0.f, 0.f, 0.f, 0.f};
                p = __builtin_amdgcn_mfma_f32_16x16x32_bf16(wf[(16 + ft * 2 + 0) * 64 + lane], bp0, p, 0, 0, 0);
                p = __builtin_amdgcn_mfma_f32_16x16x32_bf16(wf[(16 + ft * 2 + 1) * 64 + lane], bp1, p, 0, 0, 0);
                if (vo < n) {
                    float4 b4 = *(const float4*)&sEps[192 + ft * 16 + gg * 4];
                    float4 o = make_float4(p[0] + b4.x, p[1] + b4.y, p[2] + b4.z, p[3] + b4.w);
                    *(float4*)&pred_out[(size_t)vo * DD + ft * 16 + gg * 4] = o;
                }
            }
        }

        grp = __shfl(gnext, 0);
    }
}

extern "C" void kernel_launch(void* const* d_in, const int* in_sizes, int n_in,
                              void* d_out, int out_size, void* d_ws, size_t ws_size,
                              hipStream_t stream) {
    const float* feats  = (const float*)d_in[0];
    const int*   src    = (const int*)d_in[1];
    const int*   dst    = (const int*)d_in[2];
    const float* conv_W = (const float*)d_in[3];
    const float* conv_b = (const float*)d_in[4];
    const float* res_W  = (const float*)d_in[5];
    const float* res_b  = (const float*)d_in[6];
    const float* ln_g   = (const float*)d_in[7];
    const float* ln_b   = (const float*)d_in[8];
    const float* pred_W = (const float*)d_in[9];
    const float* pred_b = (const float*)d_in[10];

    int N = in_sizes[0] / DD;
    int E = in_sizes[1];

    int nbuk = (N + (1 << BSHIFT) - 1) >> BSHIFT;        // 782
    int ce   = (E + NBLK - 1) / NBLK;
    int L    = nbuk * NBLK * 2;                          // 200192
    int nb   = (L + 255) / 256;                          // 783 (<=1024 for scan2p)
    int ngrp = (N + 15) >> 4;                            // 6250
    int chunk = (ngrp + NCTR - 1) / NCTR;                // 98

    // ---- workspace layout (~58 MB) ----
    int*   rowptr = (int*)d_ws;                          // N+1
    int*   cnt    = rowptr + (N + 1);                    // MAXBUK*NBLK*2 (1 MB)
    int*   bsA    = cnt + MAXBUK * NBLK * 2;             // 1024
    int*   wctr   = bsA + 1024;                          // 3*64*32 = 6144
    int*   esrc   = wctr + 3 * NCTR * 32;                // E
    float* outn   = (float*)(esrc + E);                  // N
    float* inn    = outn + N;                            // N
    float* rs     = inn + N;                             // N
    float* base   = (float*)(((uintptr_t)(rs + N) + 15) & ~(uintptr_t)15);
    unsigned short* hsA = (unsigned short*)base;                     // N*64 bf16
    unsigned short* hsB = (unsigned short*)(base + (size_t)N * 32);  // N*64 bf16
    float* hfin  = base + (size_t)N * 64;                // N*64 fp32
    // partition scratch aliases hfin (dead before layer-0 writes hfin)
    unsigned int*  partD = (unsigned int*)hfin;                      // E uints
    unsigned char* partS = (unsigned char*)(partD + E);              // E bytes

    part_count  <<<NBLK, 256, 0, stream>>>(src, dst, cnt, wctr, E, nbuk, ce, chunk);
    scan1p      <<<nb, 256, 0, stream>>>(cnt, bsA, L);
    scan2p      <<<1, 1024, 0, stream>>>(bsA, nb);
    part_scatter<<<NBLK, 256, 0, stream>>>(src, dst, cnt, bsA, partD, partS, E, nbuk, ce);
    bucket_all  <<<nbuk, 256, 0, stream>>>(partD, partS, cnt, bsA, feats, rowptr, esrc,
                                           inn, outn, rs, hsA, E, nbuk, N);

    // L1: hsA->hsB ; L2: hsB->hsA ; L3: hsA->(pred d_out), hs_out unused
    const unsigned short* ins[3]  = {hsA, hsB, hsA};
    unsigned short*       outs[3] = {hsB, hsA, hsB};
    for (int l = 0; l < 3; ++l) {
        gcn_kernel<<<1024, 256, 0, stream>>>(
            rowptr, esrc, inn, rs, outn, ins[l],
            conv_W + (size_t)l * DD * DD, conv_b + (size_t)l * DD,
            res_W  + (size_t)l * DD * DD, res_b  + (size_t)l * DD,
            pred_W, pred_b,
            ln_g   + (size_t)l * DD,      ln_b   + (size_t)l * DD,
            outs[l], hfin, (float*)d_out, wctr + l * NCTR * 32, chunk,
            (l == 0) ? 1 : 0, (l == 2) ? 1 : 0, N);
    }
}

// Round 10
// 284.894 us; speedup vs baseline: 1.9463x; 1.0220x over previous
//
#include <hip/hip_runtime.h>
#include <hip/hip_bf16.h>

#define DD 64
#define NBLK 256          // partition pass blocks (full chip: 1 block/CU)
#define MAXBUK 1024       // max buckets => supports n <= 131072 (problem: n = 100000)
#define BSHIFT 7          // 128 nodes per bucket
#define NCTR 64           // steal counters per layer (separate 128B lines)

typedef __attribute__((ext_vector_type(8))) short short8v;  // 8 bf16 MFMA A/B frag
typedef __attribute__((ext_vector_type(4))) float f32x4;    // MFMA C/D frag

__device__ __forceinline__ unsigned pk_bf16(float a, float b) {
    __hip_bfloat162 h = __float22bfloat162_rn(make_float2(a, b));
    unsigned u; __builtin_memcpy(&u, &h, 4); return u;
}
__device__ __forceinline__ short f2bf_s(float f) {   // RNE scalar (startup only)
    union { float f; unsigned u; } x; x.f = f;
    unsigned r = x.u + 0x7fff + ((x.u >> 16) & 1);
    return (short)(r >> 16);
}
__device__ __forceinline__ float bf_lo(unsigned u) { return __int_as_float(u << 16); }
__device__ __forceinline__ float bf_hi(unsigned u) { return __int_as_float(u & 0xffff0000u); }
__device__ __forceinline__ short8v u4_to_s8(uint4 u) {
    union { uint4 u; short8v s; } x; x.u = u; return x.s;
}

// =====================================================================
// CSR build, original node space — zero global atomics, 4 build
// dispatches (R10: NBLK 128->256 full-chip streaming; scan2p dispatch
// removed — consumers re-scan bsums in LDS via scan_bs, ~1us each).
// gcn = R9 body (53.4us/layer = measured random-line-rate floor).
// =====================================================================

// cooperative exclusive scan of bsums[nb] into LDS sbs[] (nb <= 2048)
__device__ void scan_bs(const int* __restrict__ bsums, int nb,
                        int* __restrict__ sbs, int* __restrict__ part) {
    int tid = threadIdx.x;
    int k = (nb + 255) >> 8;
    int base = tid * k;
    int s = 0;
    for (int j = 0; j < k; ++j) {
        int i = base + j;
        int v = (i < nb) ? bsums[i] : 0;
        sbs[i] = v;
        s += v;
    }
    part[tid] = s;
    __syncthreads();
    for (int off = 1; off < 256; off <<= 1) {
        int t = (tid >= off) ? part[tid - off] : 0;
        __syncthreads();
        part[tid] += t;
        __syncthreads();
    }
    int run = part[tid] - s;   // exclusive prefix of this thread's segment
    for (int j = 0; j < k; ++j) {
        int i = base + j;
        int v = sbs[i];
        sbs[i] = run;
        run += v;
    }
    __syncthreads();
}

__global__ __launch_bounds__(256) void part_count(
        const int* __restrict__ src, const int* __restrict__ dst,
        int* __restrict__ cnt, int* __restrict__ wctr, int E, int nbuk, int ce,
        int chunk) {
    __shared__ int hd[MAXBUK], hs[MAXBUK];
    // seed 3 layer-banks of 64 steal counters, each on its own 128B line
    if (blockIdx.x == 0) {
        for (int i = threadIdx.x; i < 3 * NCTR; i += 256)
            wctr[i * 32] = (i & (NCTR - 1)) * chunk;
    }
    for (int i = threadIdx.x; i < MAXBUK; i += 256) { hd[i] = 0; hs[i] = 0; }
    __syncthreads();
    int e0 = blockIdx.x * ce;
    int e1 = min(e0 + ce, E);
    for (int e = e0 + (int)threadIdx.x; e < e1; e += 256) {
        atomicAdd(&hd[dst[e] >> BSHIFT], 1);
        atomicAdd(&hs[src[e] >> BSHIFT], 1);
    }
    __syncthreads();
    int L2 = nbuk * NBLK;
    // [bucket][block] layout -> flat exclusive scan yields global offsets
    for (int b = threadIdx.x; b < nbuk; b += 256) {
        cnt[b * NBLK + blockIdx.x]      = hd[b];
        cnt[L2 + b * NBLK + blockIdx.x] = hs[b];
    }
}

__global__ void scan1p(int* __restrict__ a, int* __restrict__ bsums, int L) {
    __shared__ int tmp[256];
    int gid = blockIdx.x * 256 + threadIdx.x;
    int v = (gid < L) ? a[gid] : 0;
    tmp[threadIdx.x] = v;
    __syncthreads();
    for (int off = 1; off < 256; off <<= 1) {
        int t = (threadIdx.x >= off) ? tmp[threadIdx.x - off] : 0;
        __syncthreads();
        tmp[threadIdx.x] += t;
        __syncthreads();
    }
    if (gid < L) a[gid] = tmp[threadIdx.x] - v;
    if (threadIdx.x == 255) bsums[blockIdx.x] = tmp[255];
}

__global__ __launch_bounds__(256) void part_scatter(
        const int* __restrict__ src, const int* __restrict__ dst,
        const int* __restrict__ cnt, const int* __restrict__ bsums,
        unsigned int* __restrict__ partD, unsigned char* __restrict__ partS,
        int E, int nbuk, int ce, int nb) {
    __shared__ int cd[MAXBUK], cs[MAXBUK];
    __shared__ int sbs[2048], part[256];
    scan_bs(bsums, nb, sbs, part);
    int L2 = nbuk * NBLK;
    for (int b = threadIdx.x; b < nbuk; b += 256) {
        int i0 = b * NBLK + blockIdx.x;
        int i1 = L2 + b * NBLK + blockIdx.x;
        cd[b] = cnt[i0] + sbs[i0 >> 8];
        cs[b] = cnt[i1] + sbs[i1 >> 8] - E;
    }
    __syncthreads();
    int e0 = blockIdx.x * ce;
    int e1 = min(e0 + ce, E);
    for (int e = e0 + (int)threadIdx.x; e < e1; e += 256) {
        int s = src[e], d = dst[e];
        int pd = atomicAdd(&cd[d >> BSHIFT], 1);
        partD[pd] = ((unsigned)(d & 127) << 17) | (unsigned)s;
        int ps = atomicAdd(&cs[s >> BSHIFT], 1);
        partS[ps] = (unsigned char)(s & 127);
    }
}

// ---- fused per-bucket finalize: in-hist -> rowptr/inn + esrc scatter,
//      out-hist -> outn/rs, AND hs = feats*outn (scale fused). ----
__global__ __launch_bounds__(256) void bucket_all(
        const unsigned int* __restrict__ partD, const unsigned char* __restrict__ partS,
        const int* __restrict__ cnt, const int* __restrict__ bsums,
        const float* __restrict__ feats,
        int* __restrict__ rowptr, int* __restrict__ esrc,
        float* __restrict__ inn, float* __restrict__ outn, float* __restrict__ rs,
        unsigned short* __restrict__ hsv,
        int E, int nbuk, int n, int nb) {
    __shared__ int hi[128], sc[128], cu[128], ho[128];
    __shared__ float son[128];
    __shared__ int sbs[2048], part[256];
    scan_bs(bsums, nb, sbs, part);
    int b = blockIdx.x, tid = threadIdx.x;
    int L2 = nbuk * NBLK;
    int i0 = b * NBLK, i1 = (b + 1) * NBLK;
    int e0 = cnt[i0] + sbs[i0 >> 8];
    int e1 = (b + 1 < nbuk) ? (cnt[i1] + sbs[i1 >> 8]) : E;
    int f0 = cnt[L2 + i0] + sbs[(L2 + i0) >> 8] - E;
    int f1 = (b + 1 < nbuk) ? (cnt[L2 + i1] + sbs[(L2 + i1) >> 8] - E) : E;
    if (tid < 128) { hi[tid] = 0; ho[tid] = 0; }
    __syncthreads();
    for (int e = e0 + tid; e < e1; e += 256) atomicAdd(&hi[partD[e] >> 17], 1);
    for (int e = f0 + tid; e < f1; e += 256) atomicAdd(&ho[(int)partS[e]], 1);
    __syncthreads();
    if (tid < 128) sc[tid] = hi[tid];
    __syncthreads();
    for (int off = 1; off < 128; off <<= 1) {
        int t = (tid < 128 && tid >= off) ? sc[tid - off] : 0;
        __syncthreads();
        if (tid < 128) sc[tid] += t;
        __syncthreads();
    }
    int nodeBase = b << BSHIFT;
    if (tid < 128) {
        int excl = e0 + sc[tid] - hi[tid];
        cu[tid] = excl;
        float oc = (float)max(ho[tid], 1);
        float on = rsqrtf(oc);
        son[tid] = on;
        int v = nodeBase + tid;
        if (v < n) {
            rowptr[v] = excl;
            inn[v] = rsqrtf((float)max(hi[tid], 1));
            outn[v] = on;
            rs[v]   = sqrtf(oc);
        }
    }
    if (b == 0 && tid == 0) rowptr[n] = E;
    __syncthreads();
    // esrc scatter
    for (int e = e0 + tid; e < e1; e += 256) {
        unsigned u = partD[e];
        int p = atomicAdd(&cu[u >> 17], 1);
        esrc[p] = (int)(u & 0x1FFFFu);
    }
    // fused scale: hs[v] = bf16(feats[v] * outn[v]) for the 128 bucket nodes
    for (int idx = tid; idx < 128 * 8; idx += 256) {
        int vl = idx >> 3, c = idx & 7;
        int v = nodeBase + vl;
        if (v < n) {
            float s = son[vl];
            const float4* fp = (const float4*)(feats + (size_t)v * DD) + c * 2;
            float4 g0 = fp[0], g1 = fp[1];
            uint4 o;
            o.x = pk_bf16(g0.x * s, g0.y * s); o.y = pk_bf16(g0.z * s, g0.w * s);
            o.z = pk_bf16(g1.x * s, g1.y * s); o.w = pk_bf16(g1.z * s, g1.w * s);
            *(uint4*)&hsv[(size_t)v * DD + c * 8] = o;
        }
    }
}

// ---------------- fused per-layer kernel: R9 body (verified 53.4us) ---------
__global__ __launch_bounds__(256) void gcn_kernel(
    const int* __restrict__ rowptr, const int* __restrict__ esrc,
    const float* __restrict__ inn, const float* __restrict__ rs,
    const float* __restrict__ outn,
    const unsigned short* __restrict__ hs_in,
    const float* __restrict__ Wc, const float* __restrict__ bc,
    const float* __restrict__ Wr, const float* __restrict__ br,
    const float* __restrict__ Wp, const float* __restrict__ pb,
    const float* __restrict__ g, const float* __restrict__ bb,
    unsigned short* __restrict__ hs_out, float* __restrict__ h_final,
    float* __restrict__ pred_out, int* __restrict__ wctr, int chunk,
    int first, int last, int n)
{
    __shared__ __align__(16) short sWf[24 * 64 * 8];  // 24 A-frags (Wc|Wr|Wp) x 64 lanes x 8 bf16
    __shared__ __align__(16) short sXa[4][16 * 72];   // per-wave 16-node bf16 rows (72-short pad)
    __shared__ float sEps[4 * 64];                    // bias | ln_g | ln_b | pred_b

    int lane = threadIdx.x & 63;
    int wave = threadIdx.x >> 6;        // 0..3
    int q   = lane & 15;                // mfma: node id
    int gg  = lane >> 4;                // mfma: k/feat quad
    int q8  = lane & 7;                 // gather: 16B chunk (feats q8*8..+7)
    int o8  = lane >> 3;                // gather: node-in-half 0..7

    for (int idx = threadIdx.x; idx < 64; idx += blockDim.x) {
        sEps[idx]       = bc[idx] + br[idx];
        sEps[64 + idx]  = g[idx];
        sEps[128 + idx] = bb[idx];
        sEps[192 + idx] = pb[idx];
    }
    // A-frags: f = mat*8 + ft*2 + kc ; elem j = W[kc*32+gg*8+j][ft*16+q]
    for (int f = wave * 6; f < wave * 6 + 6; ++f) {
        int mat = f >> 3, ft = (f >> 1) & 3, kc = f & 1;
        const float* Ws = (mat == 0) ? Wc : (mat == 1) ? Wr : Wp;
        int feat = ft * 16 + q;
        int k0 = kc * 32 + gg * 8;
        short8v fr;
        #pragma unroll
        for (int j = 0; j < 8; ++j) fr[j] = f2bf_s(Ws[(k0 + j) * DD + feat]);
        *(short8v*)&sWf[(f * 64 + lane) * 8] = fr;
    }
    __syncthreads();

    short* xrow_w = &sXa[wave][0];
    const short8v* wf = (const short8v*)sWf;
    int ngrp = (n + 15) >> 4;

    // distributed steal: counter c on its own 128B line; pool = groups
    // [c*chunk, min((c+1)*chunk, ngrp)). ~98 atomics/line, prefetched.
    int c = blockIdx.x & (NCTR - 1);
    int* ctr = wctr + c * 32;
    int lim = min((c + 1) * chunk, ngrp);

    int grp = 0;
    if (lane == 0) grp = atomicAdd(ctr, 1);
    grp = __shfl(grp, 0);

    while (grp < lim) {
        int gnext = 0;
        if (lane == 0) gnext = atomicAdd(ctr, 1);   // overlaps entire group body

        int vbase = grp << 4;
        int vo = vbase + q;
        int vsel = min(vo, n - 1);

        // self row B-frags (raw bf16), issued early to overlap gather
        const uint4* hrow = (const uint4*)(hs_in + (size_t)vsel * DD);
        uint4 bh0u = hrow[gg];
        uint4 bh1u = hrow[4 + gg];
        float rsv  = rs[vsel];
        float innv = inn[vsel];

        // rowptr for the 16 nodes; per-lane start/deg for both halves
        int rp = rowptr[min(vbase + min(lane, 16), n)];
        int stA = __shfl(rp, o8);     int dgA = __shfl(rp, o8 + 1) - stA;
        int stB = __shfl(rp, o8 + 8); int dgB = __shfl(rp, o8 + 9) - stB;

        #pragma unroll
        for (int hh = 0; hh < 2; ++hh) {
            int st = hh ? stB : stA;
            int dg = hh ? dgB : dgA;
            // wave-uniform max degree over this half's 8 nodes
            int mdg = dg;
            mdg = max(mdg, __shfl_xor(mdg, 8));
            mdg = max(mdg, __shfl_xor(mdg, 16));
            mdg = max(mdg, __shfl_xor(mdg, 32));

            float a[8];
            #pragma unroll
            for (int cc = 0; cc < 8; ++cc) a[cc] = 0.0f;

            int id0 = (0 < dg) ? esrc[st + 0] : 0;  float m0 = (0 < dg) ? 1.f : 0.f;
            int id1 = (1 < dg) ? esrc[st + 1] : 0;  float m1 = (1 < dg) ? 1.f : 0.f;
            int id2 = (2 < dg) ? esrc[st + 2] : 0;  float m2 = (2 < dg) ? 1.f : 0.f;
            int id3 = (3 < dg) ? esrc[st + 3] : 0;  float m3 = (3 < dg) ? 1.f : 0.f;

            for (int t = 0; t < mdg; t += 4) {
                // 4 independent 16B row-chunk loads (wave: 4 x 1KB coalesced)
                uint4 r0 = *(const uint4*)(hs_in + (size_t)id0 * DD + q8 * 8);
                uint4 r1 = *(const uint4*)(hs_in + (size_t)id1 * DD + q8 * 8);
                uint4 r2 = *(const uint4*)(hs_in + (size_t)id2 * DD + q8 * 8);
                uint4 r3 = *(const uint4*)(hs_in + (size_t)id3 * DD + q8 * 8);
                float c0 = m0, c1 = m1, c2 = m2, c3 = m3;
                // prefetch next 4 edge indices (overlap row loads)
                int t4 = t + 4;
                id0 = (t4 + 0 < dg) ? esrc[st + t4 + 0] : 0;  m0 = (t4 + 0 < dg) ? 1.f : 0.f;
                id1 = (t4 + 1 < dg) ? esrc[st + t4 + 1] : 0;  m1 = (t4 + 1 < dg) ? 1.f : 0.f;
                id2 = (t4 + 2 < dg) ? esrc[st + t4 + 2] : 0;  m2 = (t4 + 2 < dg) ? 1.f : 0.f;
                id3 = (t4 + 3 < dg) ? esrc[st + t4 + 3] : 0;  m3 = (t4 + 3 < dg) ? 1.f : 0.f;
                // accumulate
                a[0] = fmaf(bf_lo(r0.x), c0, a[0]); a[1] = fmaf(bf_hi(r0.x), c0, a[1]);
                a[2] = fmaf(bf_lo(r0.y), c0, a[2]); a[3] = fmaf(bf_hi(r0.y), c0, a[3]);
                a[4] = fmaf(bf_lo(r0.z), c0, a[4]); a[5] = fmaf(bf_hi(r0.z), c0, a[5]);
                a[6] = fmaf(bf_lo(r0.w), c0, a[6]); a[7] = fmaf(bf_hi(r0.w), c0, a[7]);
                a[0] = fmaf(bf_lo(r1.x), c1, a[0]); a[1] = fmaf(bf_hi(r1.x), c1, a[1]);
                a[2] = fmaf(bf_lo(r1.y), c1, a[2]); a[3] = fmaf(bf_hi(r1.y), c1, a[3]);
                a[4] = fmaf(bf_lo(r1.z), c1, a[4]); a[5] = fmaf(bf_hi(r1.z), c1, a[5]);
                a[6] = fmaf(bf_lo(r1.w), c1, a[6]); a[7] = fmaf(bf_hi(r1.w), c1, a[7]);
                a[0] = fmaf(bf_lo(r2.x), c2, a[0]); a[1] = fmaf(bf_hi(r2.x), c2, a[1]);
                a[2] = fmaf(bf_lo(r2.y), c2, a[2]); a[3] = fmaf(bf_hi(r2.y), c2, a[3]);
                a[4] = fmaf(bf_lo(r2.z), c2, a[4]); a[5] = fmaf(bf_hi(r2.z), c2, a[5]);
                a[6] = fmaf(bf_lo(r2.w), c2, a[6]); a[7] = fmaf(bf_hi(r2.w), c2, a[7]);
                a[0] = fmaf(bf_lo(r3.x), c3, a[0]); a[1] = fmaf(bf_hi(r3.x), c3, a[1]);
                a[2] = fmaf(bf_lo(r3.y), c3, a[2]); a[3] = fmaf(bf_hi(r3.y), c3, a[3]);
                a[4] = fmaf(bf_lo(r3.z), c3, a[4]); a[5] = fmaf(bf_hi(r3.z), c3, a[5]);
                a[6] = fmaf(bf_lo(r3.w), c3, a[6]); a[7] = fmaf(bf_hi(r3.w), c3, a[7]);
            }

            // lane holds its node-chunk's final raw sums; pack + one LDS write
            uint4 w4;
            w4.x = pk_bf16(a[0], a[1]); w4.y = pk_bf16(a[2], a[3]);
            w4.z = pk_bf16(a[4], a[5]); w4.w = pk_bf16(a[6], a[7]);
            *(uint4*)&xrow_w[(hh * 8 + o8) * 72 + q8 * 8] = w4;
        }

        // ---- B-frags + 16 MFMA (separate conv/res accumulators) ----
        const short* xr = &xrow_w[q * 72];
        short8v ba0 = *(const short8v*)&xr[gg * 8];
        short8v ba1 = *(const short8v*)&xr[32 + gg * 8];
        short8v sh0 = u4_to_s8(bh0u);
        short8v sh1 = u4_to_s8(bh1u);

        f32x4 accC[4], accR[4];
        #pragma unroll
        for (int ft = 0; ft < 4; ++ft) {
            f32x4 cq = {0.f, 0.f, 0.f, 0.f};
            cq = __builtin_amdgcn_mfma_f32_16x16x32_bf16(wf[(ft * 2 + 0) * 64 + lane], ba0, cq, 0, 0, 0);
            cq = __builtin_amdgcn_mfma_f32_16x16x32_bf16(wf[(ft * 2 + 1) * 64 + lane], ba1, cq, 0, 0, 0);
            accC[ft] = cq;
            f32x4 r = {0.f, 0.f, 0.f, 0.f};
            r = __builtin_amdgcn_mfma_f32_16x16x32_bf16(wf[(8 + ft * 2 + 0) * 64 + lane], sh0, r, 0, 0, 0);
            r = __builtin_amdgcn_mfma_f32_16x16x32_bf16(wf[(8 + ft * 2 + 1) * 64 + lane], sh1, r, 0, 0, 0);
            accR[ft] = r;
        }

        // ---- combine (inn*conv + rs*res + bias) + LayerNorm + relu ----
        f32x4 ac[4];
        #pragma unroll
        for (int ft = 0; ft < 4; ++ft) {
            float4 b4 = *(const float4*)&sEps[ft * 16 + gg * 4];
            ac[ft][0] = fmaf(innv, accC[ft][0], fmaf(rsv, accR[ft][0], b4.x));
            ac[ft][1] = fmaf(innv, accC[ft][1], fmaf(rsv, accR[ft][1], b4.y));
            ac[ft][2] = fmaf(innv, accC[ft][2], fmaf(rsv, accR[ft][2], b4.z));
            ac[ft][3] = fmaf(innv, accC[ft][3], fmaf(rsv, accR[ft][3], b4.w));
        }
        float s = 0.f;
        #pragma unroll
        for (int ft = 0; ft < 4; ++ft) s += ac[ft][0] + ac[ft][1] + ac[ft][2] + ac[ft][3];
        s += __shfl_xor(s, 16); s += __shfl_xor(s, 32);
        float mu = s * (1.0f / 64.0f);
        float vsum = 0.f;
        #pragma unroll
        for (int ft = 0; ft < 4; ++ft) {
            #pragma unroll
            for (int r = 0; r < 4; ++r) { float d = ac[ft][r] - mu; vsum += d * d; }
        }
        vsum += __shfl_xor(vsum, 16); vsum += __shfl_xor(vsum, 32);
        float rinv = rsqrtf(vsum * (1.0f / 64.0f) + 1e-5f);

        float4 yv[4];
        #pragma unroll
        for (int ft = 0; ft < 4; ++ft) {
            float4 g4 = *(const float4*)&sEps[64 + ft * 16 + gg * 4];
            float4 c4 = *(const float4*)&sEps[128 + ft * 16 + gg * 4];
            yv[ft].x = fmaxf((ac[ft][0] - mu) * rinv * g4.x + c4.x, 0.f);
            yv[ft].y = fmaxf((ac[ft][1] - mu) * rinv * g4.y + c4.y, 0.f);
            yv[ft].z = fmaxf((ac[ft][2] - mu) * rinv * g4.z + c4.z, 0.f);
            yv[ft].w = fmaxf((ac[ft][3] - mu) * rinv * g4.w + c4.w, 0.f);
        }

        if (!last) {
            if (vo < n) {
                float on = outn[vo];
                #pragma unroll
                for (int ft = 0; ft < 4; ++ft) {
                    size_t off = (size_t)vo * DD + ft * 16 + gg * 4;
                    uint2 p;
                    p.x = pk_bf16(yv[ft].x * on, yv[ft].y * on);
                    p.y = pk_bf16(yv[ft].z * on, yv[ft].w * on);
                    *(uint2*)&hs_out[off] = p;
                    if (first) {
                        *(float4*)&h_final[off] = yv[ft];
                    } else {
                        float4 hf = *(const float4*)&h_final[off];
                        hf.x += yv[ft].x; hf.y += yv[ft].y;
                        hf.z += yv[ft].z; hf.w += yv[ft].w;
                        *(float4*)&h_final[off] = hf;
                    }
                }
            }
        } else {
            // fused prediction: hf = h_final + y -> LDS (bf16) -> B-frags -> 8 MFMA -> d_out
            #pragma unroll
            for (int ft = 0; ft < 4; ++ft) {
                float4 hf = make_float4(0.f, 0.f, 0.f, 0.f);
                if (vo < n) {
                    float4 old = *(const float4*)&h_final[(size_t)vo * DD + ft * 16 + gg * 4];
                    hf.x = old.x + yv[ft].x; hf.y = old.y + yv[ft].y;
                    hf.z = old.z + yv[ft].z; hf.w = old.w + yv[ft].w;
                }
                uint2 p;
                p.x = pk_bf16(hf.x, hf.y);
                p.y = pk_bf16(hf.z, hf.w);
                *(uint2*)&xrow_w[q * 72 + ft * 16 + gg * 4] = p;   // same-wave DS, in order
            }
            short8v bp0 = *(const short8v*)&xr[gg * 8];
            short8v bp1 = *(const short8v*)&xr[32 + gg * 8];
            #pragma unroll
            for (int ft = 0; ft < 4; ++ft) {
                f32x4 p = {0.f, 0.f, 0.f, 0.f};
                p = __builtin_amdgcn_mfma_f32_16x16x32_bf16(wf[(16 + ft * 2 + 0) * 64 + lane], bp0, p, 0, 0, 0);
                p = __builtin_amdgcn_mfma_f32_16x16x32_bf16(wf[(16 + ft * 2 + 1) * 64 + lane], bp1, p, 0, 0, 0);
                if (vo < n) {
                    float4 b4 = *(const float4*)&sEps[192 + ft * 16 + gg * 4];
                    float4 o = make_float4(p[0] + b4.x, p[1] + b4.y, p[2] + b4.z, p[3] + b4.w);
                    *(float4*)&pred_out[(size_t)vo * DD + ft * 16 + gg * 4] = o;
                }
            }
        }

        grp = __shfl(gnext, 0);
    }
}

extern "C" void kernel_launch(void* const* d_in, const int* in_sizes, int n_in,
                              void* d_out, int out_size, void* d_ws, size_t ws_size,
                              hipStream_t stream) {
    const float* feats  = (const float*)d_in[0];
    const int*   src    = (const int*)d_in[1];
    const int*   dst    = (const int*)d_in[2];
    const float* conv_W = (const float*)d_in[3];
    const float* conv_b = (const float*)d_in[4];
    const float* res_W  = (const float*)d_in[5];
    const float* res_b  = (const float*)d_in[6];
    const float* ln_g   = (const float*)d_in[7];
    const float* ln_b   = (const float*)d_in[8];
    const float* pred_W = (const float*)d_in[9];
    const float* pred_b = (const float*)d_in[10];

    int N = in_sizes[0] / DD;
    int E = in_sizes[1];

    int nbuk = (N + (1 << BSHIFT) - 1) >> BSHIFT;        // 782
    int ce   = (E + NBLK - 1) / NBLK;                    // 3907
    int L    = nbuk * NBLK * 2;                          // 400384
    int nb   = (L + 255) / 256;                          // 1564 (<=2048 for scan_bs)
    int ngrp = (N + 15) >> 4;                            // 6250
    int chunk = (ngrp + NCTR - 1) / NCTR;                // 98

    // ---- workspace layout (~59 MB) ----
    int*   rowptr = (int*)d_ws;                          // N+1
    int*   cnt    = rowptr + (N + 1);                    // MAXBUK*NBLK*2 (2 MB)
    int*   bsA    = cnt + MAXBUK * NBLK * 2;             // 2048
    int*   wctr   = bsA + 2048;                          // 3*64*32 = 6144
    int*   esrc   = wctr + 3 * NCTR * 32;                // E
    float* outn   = (float*)(esrc + E);                  // N
    float* inn    = outn + N;                            // N
    float* rs     = inn + N;                             // N
    float* base   = (float*)(((uintptr_t)(rs + N) + 15) & ~(uintptr_t)15);
    unsigned short* hsA = (unsigned short*)base;                     // N*64 bf16
    unsigned short* hsB = (unsigned short*)(base + (size_t)N * 32);  // N*64 bf16
    float* hfin  = base + (size_t)N * 64;                // N*64 fp32
    // partition scratch aliases hfin (dead before layer-0 writes hfin)
    unsigned int*  partD = (unsigned int*)hfin;                      // E uints
    unsigned char* partS = (unsigned char*)(partD + E);              // E bytes

    part_count  <<<NBLK, 256, 0, stream>>>(src, dst, cnt, wctr, E, nbuk, ce, chunk);
    scan1p      <<<nb, 256, 0, stream>>>(cnt, bsA, L);
    part_scatter<<<NBLK, 256, 0, stream>>>(src, dst, cnt, bsA, partD, partS, E, nbuk, ce, nb);
    bucket_all  <<<nbuk, 256, 0, stream>>>(partD, partS, cnt, bsA, feats, rowptr, esrc,
                                           inn, outn, rs, hsA, E, nbuk, N, nb);

    // L1: hsA->hsB ; L2: hsB->hsA ; L3: hsA->(pred d_out), hs_out unused
    const unsigned short* ins[3]  = {hsA, hsB, hsA};
    unsigned short*       outs[3] = {hsB, hsA, hsB};
    for (int l = 0; l < 3; ++l) {
        gcn_kernel<<<1024, 256, 0, stream>>>(
            rowptr, esrc, inn, rs, outn, ins[l],
            conv_W + (size_t)l * DD * DD, conv_b + (size_t)l * DD,
            res_W  + (size_t)l * DD * DD, res_b  + (size_t)l * DD,
            pred_W, pred_b,
            ln_g   + (size_t)l * DD,      ln_b   + (size_t)l * DD,
            outs[l], hfin, (float*)d_out, wctr + l * NCTR * 32, chunk,
            (l == 0) ? 1 : 0, (l == 2) ? 1 : 0, N);
    }
}